// Round 1
// baseline (612.961 us; speedup 1.0000x reference)
//
#include <hip/hip_runtime.h>

#define SQH 0.70710678118654752440f

static __device__ __forceinline__ int refl(int i, int l) {
    int p2 = l << 1;
    int j = i % p2;
    if (j < 0) j += p2;
    return (j >= l) ? (p2 - 1 - j) : j;
}

// c2q value at (row rr, col = 2*jj+dj) of the 2x-upsampled plane built from bands A,B.
// yh layout: (NC, 6, rh, wh, 2); nc6 = nc*6.
static __device__ __forceinline__ float c2q_val(const float* __restrict__ yh,
                                                int nc6, int A, int B,
                                                int rr, int jj, int dj,
                                                int rh, int wh) {
    int ii = rr >> 1, di = rr & 1;
    int comp = di ^ dj;
    float w1 = yh[(((nc6 + A) * rh + ii) * wh + jj) * 2 + comp];
    float w2 = yh[(((nc6 + B) * rh + ii) * wh + jj) * 2 + comp];
    float v1 = (di & dj) ? -w1 : w1;          // (1,1): d = (w2r - w1r)*s
    float v2 = (di & (dj ^ 1)) ? -w2 : w2;    // (1,0): c = (w1i - w2i)*s
    return SQH * (v1 + v2);
}

// Column inverse-filter level (colifilt), fused c2q + both branches.
// ll: (NC, r, w). yh: (NC,6,rh,wh,2), rh=r/2, wh=w/2.
// y1,y2: (NC, 2r, w).
// y1 = colifilt(ll, g0b, g0a) + colifilt(lh, g1b, g1a, hp)
// y2 = colifilt(hl, g0b, g0a) + colifilt(hh, g1b, g1a, hp)
__global__ void k_icol(const float* __restrict__ ll, const float* __restrict__ yh,
                       float* __restrict__ y1, float* __restrict__ y2,
                       const float* __restrict__ g0a, const float* __restrict__ g0b,
                       const float* __restrict__ g1a, const float* __restrict__ g1b,
                       int r, int w, int rh, int wh, int total) {
    int idx = blockIdx.x * blockDim.x + threadIdx.x;
    if (idx >= total) return;
    int x   = idx % w;
    int t1  = idx / w;
    int R   = r << 1;
    int ro  = t1 % R;
    int nc  = t1 / R;
    int p = ro & 3, i = ro >> 2;
    int parity = p & 1;
    int oddsel = (p < 2) ? 1 : 0;          // taps order: hao, hbo, hae, hbe
    const float* hLo = parity ? g0a : g0b; // ha = g0b, hb = g0a
    const float* hHi = parity ? g1a : g1b; // ha = g1b, hb = g1a
    int baseLo = parity ? 2 : 1;           // lowpass xe base
    int baseHi = parity ? 1 : 2;           // highpass xe base (swapped)

    const float* llp = ll + nc * r * w;
    int nc6 = nc * 6;
    int jj = x >> 1, dj = x & 1;

    float acc1 = 0.f, acc2 = 0.f;
#pragma unroll
    for (int t = 0; t < 5; ++t) {
        float tl = hLo[2 * t + oddsel];
        float th = hHi[2 * t + oddsel];
        int rLo = refl(baseLo + 2 * (i + t) - 5, r);
        int rHi = refl(baseHi + 2 * (i + t) - 5, r);
        // lowpass branch: ll -> y1, hl(2,3) -> y2
        acc1 += tl * llp[rLo * w + x];
        acc2 += tl * c2q_val(yh, nc6, 2, 3, rLo, jj, dj, rh, wh);
        // highpass branch: lh(0,5) -> y1, hh(1,4) -> y2
        acc1 += th * c2q_val(yh, nc6, 0, 5, rHi, jj, dj, rh, wh);
        acc2 += th * c2q_val(yh, nc6, 1, 4, rHi, jj, dj, rh, wh);
    }
    y1[idx] = acc1;
    y2[idx] = acc2;
}

// Row inverse-filter level (rowifilt), both branches fused.
// y1,y2: (NC, R, w)  ->  out: (NC, R, 2w)
__global__ void k_irow(const float* __restrict__ y1, const float* __restrict__ y2,
                       float* __restrict__ out,
                       const float* __restrict__ g0a, const float* __restrict__ g0b,
                       const float* __restrict__ g1a, const float* __restrict__ g1b,
                       int R, int w, int total) {
    int idx = blockIdx.x * blockDim.x + threadIdx.x;
    if (idx >= total) return;
    int W2 = w << 1;
    int xo = idx % W2;
    int t1 = idx / W2;
    int y  = t1 % R;
    int nc = t1 / R;
    int p = xo & 3, j = xo >> 2;
    int parity = p & 1;
    int oddsel = (p < 2) ? 1 : 0;
    const float* hLo = parity ? g0a : g0b;
    const float* hHi = parity ? g1a : g1b;
    int baseLo = parity ? 2 : 1;
    int baseHi = parity ? 1 : 2;

    const float* r1 = y1 + (nc * R + y) * w;
    const float* r2 = y2 + (nc * R + y) * w;

    float acc = 0.f;
#pragma unroll
    for (int t = 0; t < 5; ++t) {
        acc += hLo[2 * t + oddsel] * r1[refl(baseLo + 2 * (j + t) - 5, w)];
        acc += hHi[2 * t + oddsel] * r2[refl(baseHi + 2 * (j + t) - 5, w)];
    }
    out[idx] = acc;
}

// Final-level column filter (colfilter 7-tap + 5-tap), fused c2q + both branches.
// ll: (NC,H,W), yh: (NC,6,rh,wh,2) with rh=H/2, wh=W/2. y1,y2: (NC,H,W)
__global__ void k_fcol(const float* __restrict__ ll, const float* __restrict__ yh,
                       float* __restrict__ y1, float* __restrict__ y2,
                       const float* __restrict__ g0o, const float* __restrict__ g1o,
                       int H, int W, int rh, int wh, int total) {
    int idx = blockIdx.x * blockDim.x + threadIdx.x;
    if (idx >= total) return;
    int x  = idx % W;
    int t1 = idx / W;
    int i  = t1 % H;
    int nc = t1 / H;

    const float* llp = ll + nc * H * W;
    int nc6 = nc * 6;
    int jj = x >> 1, dj = x & 1;

    float acc1 = 0.f, acc2 = 0.f;
#pragma unroll
    for (int t = 0; t < 7; ++t) {
        float h = g0o[t];
        int rr = refl(i + t - 3, H);
        acc1 += h * llp[rr * W + x];
        acc2 += h * c2q_val(yh, nc6, 2, 3, rr, jj, dj, rh, wh);  // hl
    }
#pragma unroll
    for (int t = 0; t < 5; ++t) {
        float h = g1o[t];
        int rr = refl(i + t - 2, H);
        acc1 += h * c2q_val(yh, nc6, 0, 5, rr, jj, dj, rh, wh);  // lh
        acc2 += h * c2q_val(yh, nc6, 1, 4, rr, jj, dj, rh, wh);  // hh
    }
    y1[idx] = acc1;
    y2[idx] = acc2;
}

// Final-level row filter: out = rowfilter(y1,g0o) + rowfilter(y2,g1o)
__global__ void k_frow(const float* __restrict__ y1, const float* __restrict__ y2,
                       float* __restrict__ out,
                       const float* __restrict__ g0o, const float* __restrict__ g1o,
                       int H, int W, int total) {
    int idx = blockIdx.x * blockDim.x + threadIdx.x;
    if (idx >= total) return;
    int xo = idx % W;
    int t1 = idx / W;
    int y  = t1 % H;
    int nc = t1 / H;

    const float* r1 = y1 + (nc * H + y) * W;
    const float* r2 = y2 + (nc * H + y) * W;

    float acc = 0.f;
#pragma unroll
    for (int t = 0; t < 7; ++t)
        acc += g0o[t] * r1[refl(xo + t - 3, W)];
#pragma unroll
    for (int t = 0; t < 5; ++t)
        acc += g1o[t] * r2[refl(xo + t - 2, W)];
    out[idx] = acc;
}

extern "C" void kernel_launch(void* const* d_in, const int* in_sizes, int n_in,
                              void* d_out, int out_size, void* d_ws, size_t ws_size,
                              hipStream_t stream) {
    const float* yl  = (const float*)d_in[0];
    const float* yh0 = (const float*)d_in[1];
    const float* yh1 = (const float*)d_in[2];
    const float* yh2 = (const float*)d_in[3];
    const float* g0o = (const float*)d_in[4];
    const float* g1o = (const float*)d_in[5];
    const float* g0a = (const float*)d_in[6];
    const float* g0b = (const float*)d_in[7];
    const float* g1a = (const float*)d_in[8];
    const float* g1b = (const float*)d_in[9];
    float* out = (float*)d_out;

    char* ws = (char*)d_ws;
    float* bufY1 = (float*)(ws);                         // 64 MB
    float* bufY2 = (float*)(ws + (size_t)67108864);      // 64 MB
    float* bufLL = (float*)(ws + (size_t)134217728);     // 64 MB

    const int NC = 64;
    const int BLK = 256;

    // ---- Level 2: yl(128x128) + yh2 -> ll(256x256)
    {
        int r = 128, w = 128;
        int total = NC * 2 * r * w;
        k_icol<<<(total + BLK - 1) / BLK, BLK, 0, stream>>>(
            yl, yh2, bufY1, bufY2, g0a, g0b, g1a, g1b, r, w, r / 2, w / 2, total);
        int R = 2 * r;
        int total2 = NC * R * 2 * w;
        k_irow<<<(total2 + BLK - 1) / BLK, BLK, 0, stream>>>(
            bufY1, bufY2, bufLL, g0a, g0b, g1a, g1b, R, w, total2);
    }
    // ---- Level 1: ll(256x256) + yh1 -> ll(512x512)
    {
        int r = 256, w = 256;
        int total = NC * 2 * r * w;
        k_icol<<<(total + BLK - 1) / BLK, BLK, 0, stream>>>(
            bufLL, yh1, bufY1, bufY2, g0a, g0b, g1a, g1b, r, w, r / 2, w / 2, total);
        int R = 2 * r;
        int total2 = NC * R * 2 * w;
        k_irow<<<(total2 + BLK - 1) / BLK, BLK, 0, stream>>>(
            bufY1, bufY2, bufLL, g0a, g0b, g1a, g1b, R, w, total2);
    }
    // ---- Level 0: ll(512x512) + yh0 -> out(512x512)
    {
        int H = 512, W = 512;
        int total = NC * H * W;
        k_fcol<<<(total + BLK - 1) / BLK, BLK, 0, stream>>>(
            bufLL, yh0, bufY1, bufY2, g0o, g1o, H, W, H / 2, W / 2, total);
        k_frow<<<(total + BLK - 1) / BLK, BLK, 0, stream>>>(
            bufY1, bufY2, out, g0o, g1o, H, W, total);
    }
}

// Round 2
// 322.328 us; speedup vs baseline: 1.9017x; 1.9017x over previous
//
#include <hip/hip_runtime.h>

#define SQH 0.70710678118654752440f
#define NC 64

// Half-sample symmetric reflection, L a compile-time power of two.
template<int L>
static __device__ __forceinline__ int refl(int i) {
    int j = i & (2 * L - 1);
    return (j >= L) ? (2 * L - 1 - j) : j;
}

// c2q value at (row rr, col = 2*jj+dj) of the 2x-upsampled plane from bands A,B.
// yh layout: (NC, 6, RH, WH, 2); nc6 = nc*6.
template<int RH, int WH>
static __device__ __forceinline__ float c2q_val(const float* __restrict__ yh,
                                                int nc6, int A, int B,
                                                int rr, int jj, int dj) {
    int ii = rr >> 1, di = rr & 1;
    int comp = di ^ dj;
    float w1 = yh[(((nc6 + A) * RH + ii) * WH + jj) * 2 + comp];
    float w2 = yh[(((nc6 + B) * RH + ii) * WH + jj) * 2 + comp];
    float v1 = (di & dj) ? -w1 : w1;          // (1,1): d = (w2r - w1r)*s
    float v2 = (di & (dj ^ 1)) ? -w2 : w2;    // (1,0): c = (w1i - w2i)*s
    return SQH * (v1 + v2);
}

// Column inverse-filter (colifilt), fused c2q + both branches.
// ll: (NC,R_,W_). yh: (NC,6,R_/2,W_/2,2). y1,y2: (NC,2R_,W_).
// Each thread computes 4 vertically-adjacent outputs (one phase group).
template<int R_, int W_>
__global__ void k_icol(const float* __restrict__ ll, const float* __restrict__ yh,
                       float* __restrict__ y1, float* __restrict__ y2,
                       const float* __restrict__ g0a, const float* __restrict__ g0b,
                       const float* __restrict__ g1a, const float* __restrict__ g1b) {
    constexpr int RH = R_ / 2, WH = W_ / 2;
    constexpr int G = R_ / 2;     // groups of 4 output rows (2R_/4)
    int idx = blockIdx.x * blockDim.x + threadIdx.x;
    int x  = idx % W_;
    int t1 = idx / W_;
    int i  = t1 % G;
    int nc = t1 / G;

    const float* llp = ll + (size_t)nc * R_ * W_;
    int nc6 = nc * 6;
    int jj = x >> 1, dj = x & 1;

    float llE[5], llO[5], hlE[5], hlO[5], lhE[5], lhO[5], hhE[5], hhO[5];
#pragma unroll
    for (int t = 0; t < 5; ++t) {
        int rE = refl<R_>(2 * i - 4 + 2 * t);   // even-base rows (xe base 1)
        int rO = refl<R_>(2 * i - 3 + 2 * t);   // odd-base rows  (xe base 2)
        llE[t] = llp[rE * W_ + x];
        llO[t] = llp[rO * W_ + x];
        hlE[t] = c2q_val<RH, WH>(yh, nc6, 2, 3, rE, jj, dj);
        hlO[t] = c2q_val<RH, WH>(yh, nc6, 2, 3, rO, jj, dj);
        lhE[t] = c2q_val<RH, WH>(yh, nc6, 0, 5, rE, jj, dj);
        lhO[t] = c2q_val<RH, WH>(yh, nc6, 0, 5, rO, jj, dj);
        hhE[t] = c2q_val<RH, WH>(yh, nc6, 1, 4, rE, jj, dj);
        hhO[t] = c2q_val<RH, WH>(yh, nc6, 1, 4, rO, jj, dj);
    }

    float a10 = 0, a20 = 0, a11 = 0, a21 = 0, a12 = 0, a22 = 0, a13 = 0, a23 = 0;
#pragma unroll
    for (int t = 0; t < 5; ++t) {
        float b0o = g0b[2 * t + 1], a0o = g0a[2 * t + 1];
        float b0e = g0b[2 * t],     a0e = g0a[2 * t];
        float b1o = g1b[2 * t + 1], a1o = g1a[2 * t + 1];
        float b1e = g1b[2 * t],     a1e = g1a[2 * t];
        // p=0: parity0, odd taps:  lo=g0b rows E;  hi=g1b rows O
        a10 += b0o * llE[t] + b1o * lhO[t];  a20 += b0o * hlE[t] + b1o * hhO[t];
        // p=1: parity1, odd taps:  lo=g0a rows O;  hi=g1a rows E
        a11 += a0o * llO[t] + a1o * lhE[t];  a21 += a0o * hlO[t] + a1o * hhE[t];
        // p=2: parity0, even taps
        a12 += b0e * llE[t] + b1e * lhO[t];  a22 += b0e * hlE[t] + b1e * hhO[t];
        // p=3: parity1, even taps
        a13 += a0e * llO[t] + a1e * lhE[t];  a23 += a0e * hlO[t] + a1e * hhE[t];
    }
    size_t ob = ((size_t)nc * (2 * R_) + 4 * i) * W_ + x;
    y1[ob]            = a10;  y2[ob]            = a20;
    y1[ob + W_]       = a11;  y2[ob + W_]       = a21;
    y1[ob + 2 * W_]   = a12;  y2[ob + 2 * W_]   = a22;
    y1[ob + 3 * W_]   = a13;  y2[ob + 3 * W_]   = a23;
}

// Row inverse-filter (rowifilt), both branches fused.
// y1,y2: (NC,R_,W_) -> out: (NC,R_,2W_). Each thread: 4 consecutive output cols.
template<int R_, int W_>
__global__ void k_irow(const float* __restrict__ y1, const float* __restrict__ y2,
                       float* __restrict__ out,
                       const float* __restrict__ g0a, const float* __restrict__ g0b,
                       const float* __restrict__ g1a, const float* __restrict__ g1b) {
    constexpr int G = W_ / 2;     // groups of 4 output cols (2W_/4)
    int idx = blockIdx.x * blockDim.x + threadIdx.x;
    int g  = idx % G;
    int t1 = idx / G;
    int y  = t1 % R_;
    int nc = t1 / R_;

    const float* r1 = y1 + ((size_t)nc * R_ + y) * W_;
    const float* r2 = y2 + ((size_t)nc * R_ + y) * W_;

    float e1[5], o1[5], e2[5], o2[5];
#pragma unroll
    for (int t = 0; t < 5; ++t) {
        int xE = refl<W_>(2 * g - 4 + 2 * t);
        int xO = refl<W_>(2 * g - 3 + 2 * t);
        e1[t] = r1[xE];  o1[t] = r1[xO];
        e2[t] = r2[xE];  o2[t] = r2[xO];
    }
    float4 o = make_float4(0.f, 0.f, 0.f, 0.f);
#pragma unroll
    for (int t = 0; t < 5; ++t) {
        float b0o = g0b[2 * t + 1], a0o = g0a[2 * t + 1];
        float b0e = g0b[2 * t],     a0e = g0a[2 * t];
        float b1o = g1b[2 * t + 1], a1o = g1a[2 * t + 1];
        float b1e = g1b[2 * t],     a1e = g1a[2 * t];
        o.x += b0o * e1[t] + b1o * o2[t];
        o.y += a0o * o1[t] + a1o * e2[t];
        o.z += b0e * e1[t] + b1e * o2[t];
        o.w += a0e * o1[t] + a1e * e2[t];
    }
    *(float4*)(out + ((size_t)nc * R_ + y) * (2 * W_) + 4 * g) = o;
}

// Final-level column filter (7-tap low + 5-tap high), fused c2q + both branches.
// Each thread computes 4 vertically-adjacent outputs.
template<int H, int W>
__global__ void k_fcol(const float* __restrict__ ll, const float* __restrict__ yh,
                       float* __restrict__ y1, float* __restrict__ y2,
                       const float* __restrict__ g0o, const float* __restrict__ g1o) {
    constexpr int RH = H / 2, WH = W / 2;
    constexpr int G = H / 4;
    int idx = blockIdx.x * blockDim.x + threadIdx.x;
    int x  = idx % W;
    int t1 = idx / W;
    int g  = t1 % G;
    int nc = t1 / G;

    const float* llp = ll + (size_t)nc * H * W;
    int nc6 = nc * 6;
    int jj = x >> 1, dj = x & 1;

    float L[10], HL[10], LH[8], HH[8];
#pragma unroll
    for (int m = 0; m < 10; ++m) {
        int rr = refl<H>(4 * g - 3 + m);
        L[m]  = llp[rr * W + x];
        HL[m] = c2q_val<RH, WH>(yh, nc6, 2, 3, rr, jj, dj);
    }
#pragma unroll
    for (int m = 0; m < 8; ++m) {
        int rr = refl<H>(4 * g - 2 + m);
        LH[m] = c2q_val<RH, WH>(yh, nc6, 0, 5, rr, jj, dj);
        HH[m] = c2q_val<RH, WH>(yh, nc6, 1, 4, rr, jj, dj);
    }
    float a1[4] = {0, 0, 0, 0}, a2[4] = {0, 0, 0, 0};
#pragma unroll
    for (int q = 0; q < 4; ++q) {
#pragma unroll
        for (int t = 0; t < 7; ++t) {
            float h = g0o[t];
            a1[q] += h * L[q + t];
            a2[q] += h * HL[q + t];
        }
#pragma unroll
        for (int t = 0; t < 5; ++t) {
            float h = g1o[t];
            a1[q] += h * LH[q + t];
            a2[q] += h * HH[q + t];
        }
    }
    size_t ob = ((size_t)nc * H + 4 * g) * W + x;
#pragma unroll
    for (int q = 0; q < 4; ++q) {
        y1[ob + (size_t)q * W] = a1[q];
        y2[ob + (size_t)q * W] = a2[q];
    }
}

// Final-level row filter: out = rowfilter(y1,g0o) + rowfilter(y2,g1o).
// Each thread: 4 consecutive output cols, float4 store.
template<int H, int W>
__global__ void k_frow(const float* __restrict__ y1, const float* __restrict__ y2,
                       float* __restrict__ out,
                       const float* __restrict__ g0o, const float* __restrict__ g1o) {
    constexpr int G = W / 4;
    int idx = blockIdx.x * blockDim.x + threadIdx.x;
    int g  = idx % G;
    int t1 = idx / G;
    int y  = t1 % H;
    int nc = t1 / H;

    const float* r1 = y1 + ((size_t)nc * H + y) * W;
    const float* r2 = y2 + ((size_t)nc * H + y) * W;

    float A[10], B[8];
#pragma unroll
    for (int m = 0; m < 10; ++m) A[m] = r1[refl<W>(4 * g - 3 + m)];
#pragma unroll
    for (int m = 0; m < 8; ++m)  B[m] = r2[refl<W>(4 * g - 2 + m)];

    float4 o = make_float4(0.f, 0.f, 0.f, 0.f);
    float acc[4] = {0, 0, 0, 0};
#pragma unroll
    for (int q = 0; q < 4; ++q) {
#pragma unroll
        for (int t = 0; t < 7; ++t) acc[q] += g0o[t] * A[q + t];
#pragma unroll
        for (int t = 0; t < 5; ++t) acc[q] += g1o[t] * B[q + t];
    }
    o.x = acc[0]; o.y = acc[1]; o.z = acc[2]; o.w = acc[3];
    *(float4*)(out + ((size_t)nc * H + y) * W + 4 * g) = o;
}

extern "C" void kernel_launch(void* const* d_in, const int* in_sizes, int n_in,
                              void* d_out, int out_size, void* d_ws, size_t ws_size,
                              hipStream_t stream) {
    const float* yl  = (const float*)d_in[0];
    const float* yh0 = (const float*)d_in[1];
    const float* yh1 = (const float*)d_in[2];
    const float* yh2 = (const float*)d_in[3];
    const float* g0o = (const float*)d_in[4];
    const float* g1o = (const float*)d_in[5];
    const float* g0a = (const float*)d_in[6];
    const float* g0b = (const float*)d_in[7];
    const float* g1a = (const float*)d_in[8];
    const float* g1b = (const float*)d_in[9];
    float* out = (float*)d_out;

    char* ws = (char*)d_ws;
    float* bufY1 = (float*)(ws);                         // 64 MB
    float* bufY2 = (float*)(ws + (size_t)67108864);      // 64 MB
    float* bufLL = (float*)(ws + (size_t)134217728);     // 64 MB

    const int BLK = 256;

    // ---- Level 2: yl(128x128) + yh2 -> ll(256x256)
    k_icol<128, 128><<<NC * 64 * 128 / BLK, BLK, 0, stream>>>(
        yl, yh2, bufY1, bufY2, g0a, g0b, g1a, g1b);
    k_irow<256, 128><<<NC * 256 * 64 / BLK, BLK, 0, stream>>>(
        bufY1, bufY2, bufLL, g0a, g0b, g1a, g1b);

    // ---- Level 1: ll(256x256) + yh1 -> ll(512x512)
    k_icol<256, 256><<<NC * 128 * 256 / BLK, BLK, 0, stream>>>(
        bufLL, yh1, bufY1, bufY2, g0a, g0b, g1a, g1b);
    k_irow<512, 256><<<NC * 512 * 128 / BLK, BLK, 0, stream>>>(
        bufY1, bufY2, bufLL, g0a, g0b, g1a, g1b);

    // ---- Level 0: ll(512x512) + yh0 -> out(512x512)
    k_fcol<512, 512><<<NC * 128 * 512 / BLK, BLK, 0, stream>>>(
        bufLL, yh0, bufY1, bufY2, g0o, g1o);
    k_frow<512, 512><<<NC * 512 * 128 / BLK, BLK, 0, stream>>>(
        bufY1, bufY2, out, g0o, g1o);
}

// Round 3
// 296.670 us; speedup vs baseline: 2.0661x; 1.0865x over previous
//
#include <hip/hip_runtime.h>

#define SQH 0.70710678118654752440f
#define NC 64

// Half-sample symmetric reflection, L a compile-time power of two.
template<int L>
static __device__ __forceinline__ int refl(int i) {
    int j = i & (2 * L - 1);
    return (j >= L) ? (2 * L - 1 - j) : j;
}

static __device__ __forceinline__ float c2q_from(float2 w1, float2 w2, int di, int dj) {
    int comp = di ^ dj;
    float a = comp ? w1.y : w1.x;
    float b = comp ? w2.y : w2.x;
    float v1 = (di & dj) ? -a : a;          // (1,1): d = (w2r - w1r)*s
    float v2 = (di & (dj ^ 1)) ? -b : b;    // (1,0): c = (w1i - w2i)*s
    return SQH * (v1 + v2);
}

// Scalar c2q (2 loads) at row rr, col 2*jj+dj. yh: (NC,6,RH,WH,2).
template<int RH, int WH>
static __device__ __forceinline__ float c2q_val(const float* __restrict__ yh, int nc6,
                                                int A, int B, int rr, int jj, int dj) {
    int ii = rr >> 1, di = rr & 1, comp = di ^ dj;
    float w1 = yh[(((size_t)(nc6 + A) * RH + ii) * WH + jj) * 2 + comp];
    float w2 = yh[(((size_t)(nc6 + B) * RH + ii) * WH + jj) * 2 + comp];
    float v1 = (di & dj) ? -w1 : w1;
    float v2 = (di & (dj ^ 1)) ? -w2 : w2;
    return SQH * (v1 + v2);
}

// Pair c2q: rows {2*ii, 2*ii+1}; vE = value at parity diE, vO at parity diE^1.
// One float2 per band covers both rows.
template<int RH, int WH>
static __device__ __forceinline__ void c2q_pair(const float* __restrict__ yh, int nc6,
                                                int A, int B, int ii, int jj, int dj,
                                                int diE, float& vE, float& vO) {
    float2 w1 = ((const float2*)yh)[((size_t)(nc6 + A) * RH + ii) * WH + jj];
    float2 w2 = ((const float2*)yh)[((size_t)(nc6 + B) * RH + ii) * WH + jj];
    vE = c2q_from(w1, w2, diE, dj);
    vO = c2q_from(w1, w2, diE ^ 1, dj);
}

// ---- Fused inverse level: colifilt (c2q fused, both branches) -> LDS -> rowifilt.
// ll: (NC,R_,W_), yh: (NC,6,R_/2,W_/2,2) -> out: (NC,2R_,2W_). TY out rows per block.
template<int R_, int W_, int TY>
__global__ __launch_bounds__(256) void k_i(const float* __restrict__ ll,
                                           const float* __restrict__ yh,
                                           float* __restrict__ out,
                                           const float* __restrict__ g0a, const float* __restrict__ g0b,
                                           const float* __restrict__ g1a, const float* __restrict__ g1b) {
    constexpr int RH = R_ / 2, WH = W_ / 2;
    constexpr int STRIPS = W_ + 10;                 // w-cols -4 .. W_+5
    constexpr int SEP = (W_ / 2 + 8 + 7) & ~7;      // parity-split width (padded)
    constexpr int NG = TY / 4;
    __shared__ float Ye1[TY][SEP], Yo1[TY][SEP], Ye2[TY][SEP], Yo2[TY][SEP];

    int nc = blockIdx.z, nc6 = nc * 6;
    int R0 = blockIdx.y * TY, i0 = R0 >> 2;
    int tid = threadIdx.x;

    float t0a[10], t0b[10], t1a[10], t1b[10];
#pragma unroll
    for (int k = 0; k < 10; ++k) { t0a[k] = g0a[k]; t0b[k] = g0b[k]; t1a[k] = g1a[k]; t1b[k] = g1b[k]; }

    const float* llp = ll + (size_t)nc * R_ * W_;

    // ---- Stage A: column inverse filter, sliding window per column strip.
    for (int s = tid; s < STRIPS; s += blockDim.x) {
        int cw = refl<W_>(s - 4);
        int jj = cw >> 1, dj = cw & 1;
        float lE[5], lO[5], hlE[5], hlO[5], lhE[5], lhO[5], hhE[5], hhO[5];
#pragma unroll
        for (int t = 0; t < 4; ++t) {
            int rE = refl<R_>(2 * i0 - 4 + 2 * t);
            int rO = refl<R_>(2 * i0 - 3 + 2 * t);
            lE[t] = llp[(size_t)rE * W_ + cw];
            lO[t] = llp[(size_t)rO * W_ + cw];
            int ii = rE >> 1, diE = rE & 1;
            c2q_pair<RH, WH>(yh, nc6, 2, 3, ii, jj, dj, diE, hlE[t], hlO[t]);
            c2q_pair<RH, WH>(yh, nc6, 0, 5, ii, jj, dj, diE, lhE[t], lhO[t]);
            c2q_pair<RH, WH>(yh, nc6, 1, 4, ii, jj, dj, diE, hhE[t], hhO[t]);
        }
#pragma unroll
        for (int g = 0; g < NG; ++g) {
            int i = i0 + g;
            int rE = refl<R_>(2 * i + 4);
            int rO = refl<R_>(2 * i + 5);
            lE[4] = llp[(size_t)rE * W_ + cw];
            lO[4] = llp[(size_t)rO * W_ + cw];
            int ii = rE >> 1, diE = rE & 1;
            c2q_pair<RH, WH>(yh, nc6, 2, 3, ii, jj, dj, diE, hlE[4], hlO[4]);
            c2q_pair<RH, WH>(yh, nc6, 0, 5, ii, jj, dj, diE, lhE[4], lhO[4]);
            c2q_pair<RH, WH>(yh, nc6, 1, 4, ii, jj, dj, diE, hhE[4], hhO[4]);

            float a10 = 0, a20 = 0, a11 = 0, a21 = 0, a12 = 0, a22 = 0, a13 = 0, a23 = 0;
#pragma unroll
            for (int t = 0; t < 5; ++t) {
                float b0o = t0b[2 * t + 1], a0o = t0a[2 * t + 1];
                float b0e = t0b[2 * t],     a0e = t0a[2 * t];
                float b1o = t1b[2 * t + 1], a1o = t1a[2 * t + 1];
                float b1e = t1b[2 * t],     a1e = t1a[2 * t];
                a10 += b0o * lE[t] + b1o * lhO[t];  a20 += b0o * hlE[t] + b1o * hhO[t];
                a11 += a0o * lO[t] + a1o * lhE[t];  a21 += a0o * hlO[t] + a1o * hhE[t];
                a12 += b0e * lE[t] + b1e * lhO[t];  a22 += b0e * hlE[t] + b1e * hhO[t];
                a13 += a0e * lO[t] + a1e * lhE[t];  a23 += a0e * hlO[t] + a1e * hhE[t];
            }
            int k = s >> 1;
            if (s & 1) {
                Yo1[4 * g + 0][k] = a10;  Yo2[4 * g + 0][k] = a20;
                Yo1[4 * g + 1][k] = a11;  Yo2[4 * g + 1][k] = a21;
                Yo1[4 * g + 2][k] = a12;  Yo2[4 * g + 2][k] = a22;
                Yo1[4 * g + 3][k] = a13;  Yo2[4 * g + 3][k] = a23;
            } else {
                Ye1[4 * g + 0][k] = a10;  Ye2[4 * g + 0][k] = a20;
                Ye1[4 * g + 1][k] = a11;  Ye2[4 * g + 1][k] = a21;
                Ye1[4 * g + 2][k] = a12;  Ye2[4 * g + 2][k] = a22;
                Ye1[4 * g + 3][k] = a13;  Ye2[4 * g + 3][k] = a23;
            }
#pragma unroll
            for (int t = 0; t < 4; ++t) {
                lE[t] = lE[t + 1];   lO[t] = lO[t + 1];
                hlE[t] = hlE[t + 1]; hlO[t] = hlO[t + 1];
                lhE[t] = lhE[t + 1]; lhO[t] = lhO[t + 1];
                hhE[t] = hhE[t + 1]; hhO[t] = hhO[t + 1];
            }
        }
    }
    __syncthreads();

    // ---- Stage B: row inverse filter from LDS, float4 stores.
    constexpr int QW = W_ / 2;   // quads per output row
    for (int task = tid; task < TY * QW; task += blockDim.x) {
        int j = task % QW;
        int r = task / QW;
        float e1[5], o1[5], e2[5], o2[5];
#pragma unroll
        for (int t = 0; t < 5; ++t) {
            e1[t] = Ye1[r][j + t];  o1[t] = Yo1[r][j + t];
            e2[t] = Ye2[r][j + t];  o2[t] = Yo2[r][j + t];
        }
        float4 o = make_float4(0.f, 0.f, 0.f, 0.f);
#pragma unroll
        for (int t = 0; t < 5; ++t) {
            float b0o = t0b[2 * t + 1], a0o = t0a[2 * t + 1];
            float b0e = t0b[2 * t],     a0e = t0a[2 * t];
            float b1o = t1b[2 * t + 1], a1o = t1a[2 * t + 1];
            float b1e = t1b[2 * t],     a1e = t1a[2 * t];
            o.x += b0o * e1[t] + b1o * o2[t];
            o.y += a0o * o1[t] + a1o * e2[t];
            o.z += b0e * e1[t] + b1e * o2[t];
            o.w += a0e * o1[t] + a1e * e2[t];
        }
        *(float4*)(out + ((size_t)nc * (2 * R_) + R0 + r) * (2 * W_) + 4 * j) = o;
    }
}

// ---- Fused final level: colfilter(7/5-tap, c2q fused) -> LDS -> rowfilter.
// ll: (NC,H,W), yh: (NC,6,H/2,W/2,2) -> out: (NC,H,W). Tile TY x TX.
template<int H, int W, int TY, int TX>
__global__ __launch_bounds__(256) void k_f0(const float* __restrict__ ll,
                                            const float* __restrict__ yh,
                                            float* __restrict__ out,
                                            const float* __restrict__ g0o,
                                            const float* __restrict__ g1o) {
    constexpr int RH = H / 2, WH = W / 2;
    constexpr int STRIPS = TX + 6;                  // cols c0-3 .. c0+TX+2
    constexpr int SPAD = (STRIPS + 7) & ~7;
    __shared__ float Y1[TY][SPAD], Y2[TY][SPAD];

    int nc = blockIdx.z, nc6 = nc * 6;
    int c0 = blockIdx.x * TX, r0 = blockIdx.y * TY;
    int tid = threadIdx.x;

    float f0[7], f1[5];
#pragma unroll
    for (int k = 0; k < 7; ++k) f0[k] = g0o[k];
#pragma unroll
    for (int k = 0; k < 5; ++k) f1[k] = g1o[k];

    const float* llp = ll + (size_t)nc * H * W;

    // ---- Stage A: column filter, sliding window per column strip.
    for (int s = tid; s < STRIPS; s += blockDim.x) {
        int c = refl<W>(c0 - 3 + s);
        int jj = c >> 1, dj = c & 1;
        float wL[7], wHL[7], wLH[5], wHH[5];
#pragma unroll
        for (int k = 0; k < 6; ++k) {
            int rr = refl<H>(r0 - 3 + k);
            wL[k]  = llp[(size_t)rr * W + c];
            wHL[k] = c2q_val<RH, WH>(yh, nc6, 2, 3, rr, jj, dj);
        }
#pragma unroll
        for (int k = 0; k < 4; ++k) {
            int rr = refl<H>(r0 - 2 + k);
            wLH[k] = c2q_val<RH, WH>(yh, nc6, 0, 5, rr, jj, dj);
            wHH[k] = c2q_val<RH, WH>(yh, nc6, 1, 4, rr, jj, dj);
        }
#pragma unroll
        for (int ri = 0; ri < TY; ++ri) {
            int rr3 = refl<H>(r0 + ri + 3);
            int rr2 = refl<H>(r0 + ri + 2);
            wL[6]  = llp[(size_t)rr3 * W + c];
            wHL[6] = c2q_val<RH, WH>(yh, nc6, 2, 3, rr3, jj, dj);
            wLH[4] = c2q_val<RH, WH>(yh, nc6, 0, 5, rr2, jj, dj);
            wHH[4] = c2q_val<RH, WH>(yh, nc6, 1, 4, rr2, jj, dj);
            float a1 = 0.f, a2 = 0.f;
#pragma unroll
            for (int t = 0; t < 7; ++t) { a1 += f0[t] * wL[t]; a2 += f0[t] * wHL[t]; }
#pragma unroll
            for (int t = 0; t < 5; ++t) { a1 += f1[t] * wLH[t]; a2 += f1[t] * wHH[t]; }
            Y1[ri][s] = a1;
            Y2[ri][s] = a2;
#pragma unroll
            for (int t = 0; t < 6; ++t) { wL[t] = wL[t + 1]; wHL[t] = wHL[t + 1]; }
#pragma unroll
            for (int t = 0; t < 4; ++t) { wLH[t] = wLH[t + 1]; wHH[t] = wHH[t + 1]; }
        }
    }
    __syncthreads();

    // ---- Stage B: row filter from LDS, 4 cols per thread, float4 loads/stores.
#pragma unroll
    for (int pass = 0; pass < TY / 4; ++pass) {
        int r = (tid >> 6) + 4 * pass;
        int lxq = (tid & 63) * 4;
        float4 u0 = *(const float4*)&Y1[r][lxq];
        float4 u1 = *(const float4*)&Y1[r][lxq + 4];
        float4 u2 = *(const float4*)&Y1[r][lxq + 8];
        float4 v0 = *(const float4*)&Y2[r][lxq];
        float4 v1 = *(const float4*)&Y2[r][lxq + 4];
        float4 v2 = *(const float4*)&Y2[r][lxq + 8];
        float w1[12] = {u0.x, u0.y, u0.z, u0.w, u1.x, u1.y, u1.z, u1.w, u2.x, u2.y, u2.z, u2.w};
        float w2[12] = {v0.x, v0.y, v0.z, v0.w, v1.x, v1.y, v1.z, v1.w, v2.x, v2.y, v2.z, v2.w};
        float acc[4] = {0.f, 0.f, 0.f, 0.f};
#pragma unroll
        for (int q = 0; q < 4; ++q) {
#pragma unroll
            for (int t = 0; t < 7; ++t) acc[q] += f0[t] * w1[q + t];
#pragma unroll
            for (int t = 0; t < 5; ++t) acc[q] += f1[t] * w2[q + 1 + t];
        }
        *(float4*)(out + ((size_t)nc * H + r0 + r) * W + c0 + lxq) =
            make_float4(acc[0], acc[1], acc[2], acc[3]);
    }
}

extern "C" void kernel_launch(void* const* d_in, const int* in_sizes, int n_in,
                              void* d_out, int out_size, void* d_ws, size_t ws_size,
                              hipStream_t stream) {
    const float* yl  = (const float*)d_in[0];
    const float* yh0 = (const float*)d_in[1];
    const float* yh1 = (const float*)d_in[2];
    const float* yh2 = (const float*)d_in[3];
    const float* g0o = (const float*)d_in[4];
    const float* g1o = (const float*)d_in[5];
    const float* g0a = (const float*)d_in[6];
    const float* g0b = (const float*)d_in[7];
    const float* g1a = (const float*)d_in[8];
    const float* g1b = (const float*)d_in[9];
    float* out = (float*)d_out;

    char* ws = (char*)d_ws;
    float* bufA = (float*)(ws);                       // ll 256x256: 16 MB
    float* bufB = (float*)(ws + ((size_t)64 << 20));  // ll 512x512: 64 MB

    // Level 2: yl(128x128) + yh2 -> ll(256x256)
    k_i<128, 128, 16><<<dim3(1, 16, NC), 256, 0, stream>>>(yl, yh2, bufA, g0a, g0b, g1a, g1b);
    // Level 1: ll(256x256) + yh1 -> ll(512x512)
    k_i<256, 256, 16><<<dim3(1, 32, NC), 256, 0, stream>>>(bufA, yh1, bufB, g0a, g0b, g1a, g1b);
    // Level 0: ll(512x512) + yh0 -> out(512x512)
    k_f0<512, 512, 16, 256><<<dim3(2, 32, NC), 256, 0, stream>>>(bufB, yh0, out, g0o, g1o);
}

// Round 4
// 187.981 us; speedup vs baseline: 3.2608x; 1.5782x over previous
//
#include <hip/hip_runtime.h>

#define SQH 0.70710678118654752440f
#define NC 64

// Half-sample symmetric reflection, L a compile-time power of two.
// Works for args in (-2L, 2L): mask then fold.
template<int L>
static __device__ __forceinline__ int refl(int i) {
    int j = i & (2 * L - 1);
    return (j >= L) ? (2 * L - 1 - j) : j;
}

static __device__ __forceinline__ float c2q_from(float2 w1, float2 w2, int di, int dj) {
    int comp = di ^ dj;
    float a = comp ? w1.y : w1.x;
    float b = comp ? w2.y : w2.x;
    float v1 = (di & dj) ? -a : a;          // (1,1): d = (w2r - w1r)*s
    float v2 = (di & (dj ^ 1)) ? -b : b;    // (1,0): c = (w1i - w2i)*s
    return SQH * (v1 + v2);
}

// One float2 per band serves both rows of a sibling pair {2m,2m+1} after
// reflection (reflection maps arg pairs to row pairs). vE = value at the
// even arg (parity diE), vO = at the odd arg (parity diE^1).
template<int RH, int WH>
static __device__ __forceinline__ void c2q_pair(const float* __restrict__ yh, int nc6,
                                                int A, int B, int ii, int jj, int dj,
                                                int diE, float& vE, float& vO) {
    float2 w1 = ((const float2*)yh)[((size_t)(nc6 + A) * RH + ii) * WH + jj];
    float2 w2 = ((const float2*)yh)[((size_t)(nc6 + B) * RH + ii) * WH + jj];
    vE = c2q_from(w1, w2, diE, dj);
    vO = c2q_from(w1, w2, diE ^ 1, dj);
}

// ---- Fused inverse level: colifilt (c2q fused, both branches) -> LDS -> rowifilt.
// ll: (NC,R_,W_), yh: (NC,6,R_/2,W_/2,2) -> out: (NC,2R_,2W_).
// Block = full-width slab of TY output rows. No column halo (reflection stays in-slab).
template<int R_, int W_, int TY>
__global__ __launch_bounds__(256) void k_i(const float* __restrict__ ll,
                                           const float* __restrict__ yh,
                                           float* __restrict__ out,
                                           const float* __restrict__ g0a, const float* __restrict__ g0b,
                                           const float* __restrict__ g1a, const float* __restrict__ g1b) {
    constexpr int RH = R_ / 2, WH = W_ / 2;
    constexpr int PAD = 2;
    __shared__ float Y1[TY][W_ + PAD], Y2[TY][W_ + PAD];

    int slab = blockIdx.x, nc = blockIdx.y, nc6 = nc * 6;
    int R0 = slab * TY;          // output-row base (in 2R_ space)
    int i0 = R0 >> 2;            // phase-group base
    const float* llp = ll + (size_t)nc * R_ * W_;

    // ---- Stage A: column inverse filter. One task = 4 vertical outputs at one col.
    constexpr int ATASK = W_ * (TY / 4);
    for (int task = threadIdx.x; task < ATASK; task += 256) {
        int x  = task % W_;
        int gl = task / W_;
        int i  = i0 + gl;
        int jj = x >> 1, dj = x & 1;

        float lE[5], lO[5], hlE[5], hlO[5], lhE[5], lhO[5], hhE[5], hhO[5];
#pragma unroll
        for (int t = 0; t < 5; ++t) {
            int rE = refl<R_>(2 * i - 4 + 2 * t);
            int rO = refl<R_>(2 * i - 3 + 2 * t);
            lE[t] = llp[(size_t)rE * W_ + x];
            lO[t] = llp[(size_t)rO * W_ + x];
            int ii = rE >> 1, diE = rE & 1;
            c2q_pair<RH, WH>(yh, nc6, 2, 3, ii, jj, dj, diE, hlE[t], hlO[t]);
            c2q_pair<RH, WH>(yh, nc6, 0, 5, ii, jj, dj, diE, lhE[t], lhO[t]);
            c2q_pair<RH, WH>(yh, nc6, 1, 4, ii, jj, dj, diE, hhE[t], hhO[t]);
        }
        float a10 = 0, a20 = 0, a11 = 0, a21 = 0, a12 = 0, a22 = 0, a13 = 0, a23 = 0;
#pragma unroll
        for (int t = 0; t < 5; ++t) {
            float b0o = g0b[2 * t + 1], a0o = g0a[2 * t + 1];
            float b0e = g0b[2 * t],     a0e = g0a[2 * t];
            float b1o = g1b[2 * t + 1], a1o = g1a[2 * t + 1];
            float b1e = g1b[2 * t],     a1e = g1a[2 * t];
            a10 += b0o * lE[t] + b1o * lhO[t];  a20 += b0o * hlE[t] + b1o * hhO[t];
            a11 += a0o * lO[t] + a1o * lhE[t];  a21 += a0o * hlO[t] + a1o * hhE[t];
            a12 += b0e * lE[t] + b1e * lhO[t];  a22 += b0e * hlE[t] + b1e * hhO[t];
            a13 += a0e * lO[t] + a1e * lhE[t];  a23 += a0e * hlO[t] + a1e * hhE[t];
        }
        int rl = 4 * gl;
        Y1[rl + 0][x] = a10;  Y2[rl + 0][x] = a20;
        Y1[rl + 1][x] = a11;  Y2[rl + 1][x] = a21;
        Y1[rl + 2][x] = a12;  Y2[rl + 2][x] = a22;
        Y1[rl + 3][x] = a13;  Y2[rl + 3][x] = a23;
    }
    __syncthreads();

    // ---- Stage B: row inverse filter from LDS. One task = 4 output cols (float4 store).
    constexpr int QW = W_ / 2;   // quads per output row (2W_/4)
    for (int task = threadIdx.x; task < TY * QW; task += 256) {
        int j = task % QW;
        int r = task / QW;
        float e1[5], o1[5], e2[5], o2[5];
#pragma unroll
        for (int t = 0; t < 5; ++t) {
            int xE = refl<W_>(2 * j - 4 + 2 * t);
            int xO = refl<W_>(2 * j - 3 + 2 * t);
            e1[t] = Y1[r][xE];  o1[t] = Y1[r][xO];
            e2[t] = Y2[r][xE];  o2[t] = Y2[r][xO];
        }
        float4 o = make_float4(0.f, 0.f, 0.f, 0.f);
#pragma unroll
        for (int t = 0; t < 5; ++t) {
            float b0o = g0b[2 * t + 1], a0o = g0a[2 * t + 1];
            float b0e = g0b[2 * t],     a0e = g0a[2 * t];
            float b1o = g1b[2 * t + 1], a1o = g1a[2 * t + 1];
            float b1e = g1b[2 * t],     a1e = g1a[2 * t];
            o.x += b0o * e1[t] + b1o * o2[t];
            o.y += a0o * o1[t] + a1o * e2[t];
            o.z += b0e * e1[t] + b1e * o2[t];
            o.w += a0e * o1[t] + a1e * e2[t];
        }
        *(float4*)(out + ((size_t)nc * (2 * R_) + R0 + r) * (2 * W_) + 4 * j) = o;
    }
}

// ---- Fused final level: colfilter(7/5-tap, c2q fused) -> LDS -> rowfilter.
// ll: (NC,H,W), yh: (NC,6,H/2,W/2,2) -> out: (NC,H,W). Full-width slab of TY rows.
template<int H, int W, int TY>
__global__ __launch_bounds__(256) void k_f0(const float* __restrict__ ll,
                                            const float* __restrict__ yh,
                                            float* __restrict__ out,
                                            const float* __restrict__ g0o,
                                            const float* __restrict__ g1o) {
    constexpr int RH = H / 2, WH = W / 2;
    constexpr int PAD = 2;
    __shared__ float Y1[TY][W + PAD], Y2[TY][W + PAD];

    int slab = blockIdx.x, nc = blockIdx.y, nc6 = nc * 6;
    int r0 = slab * TY;
    const float* llp = ll + (size_t)nc * H * W;

    float f0[7], f1[5];
#pragma unroll
    for (int k = 0; k < 7; ++k) f0[k] = g0o[k];
#pragma unroll
    for (int k = 0; k < 5; ++k) f1[k] = g1o[k];

    // ---- Stage A: column filter. One task = 4 vertical outputs at one col.
    constexpr int ATASK = W * (TY / 4);
    for (int task = threadIdx.x; task < ATASK; task += 256) {
        int x  = task % W;
        int gl = task / W;
        int gg = (r0 >> 2) + gl;
        int jj = x >> 1, dj = x & 1;

        float L[10], HL[10], LH[8], HH[8];
#pragma unroll
        for (int t = 0; t < 10; ++t)
            L[t] = llp[(size_t)refl<H>(4 * gg - 3 + t) * W + x];
        // HL window rows = args 4gg-3 .. 4gg+6 -> 6 sibling pairs (ends partial).
#pragma unroll
        for (int pp = 0; pp < 6; ++pp) {
            int rE = refl<H>(4 * gg - 4 + 2 * pp);
            int ii = rE >> 1, diE = rE & 1;
            float vE, vO;
            c2q_pair<RH, WH>(yh, nc6, 2, 3, ii, jj, dj, diE, vE, vO);
            if (pp > 0) HL[2 * pp - 1] = vE;
            if (pp < 5) HL[2 * pp]     = vO;
        }
        // LH/HH window rows = args 4gg-2 .. 4gg+5 -> exactly 4 full pairs.
#pragma unroll
        for (int pp = 0; pp < 4; ++pp) {
            int rE = refl<H>(4 * gg - 2 + 2 * pp);
            int ii = rE >> 1, diE = rE & 1;
            c2q_pair<RH, WH>(yh, nc6, 0, 5, ii, jj, dj, diE, LH[2 * pp], LH[2 * pp + 1]);
            c2q_pair<RH, WH>(yh, nc6, 1, 4, ii, jj, dj, diE, HH[2 * pp], HH[2 * pp + 1]);
        }
        float a1[4] = {0, 0, 0, 0}, a2[4] = {0, 0, 0, 0};
#pragma unroll
        for (int q = 0; q < 4; ++q) {
#pragma unroll
            for (int t = 0; t < 7; ++t) { a1[q] += f0[t] * L[q + t];  a2[q] += f0[t] * HL[q + t]; }
#pragma unroll
            for (int t = 0; t < 5; ++t) { a1[q] += f1[t] * LH[q + t]; a2[q] += f1[t] * HH[q + t]; }
        }
        int rl = 4 * gl;
#pragma unroll
        for (int q = 0; q < 4; ++q) {
            Y1[rl + q][x] = a1[q];
            Y2[rl + q][x] = a2[q];
        }
    }
    __syncthreads();

    // ---- Stage B: row filter from LDS. One task = 2 output cols (float2 store,
    // lane-stride-2 LDS reads = 2-way = conflict-free).
    constexpr int PW = W / 2;
    for (int task = threadIdx.x; task < TY * PW; task += 256) {
        int jp = task % PW;
        int r  = task / PW;
        int c0 = 2 * jp;
        float A[8], B[6];
#pragma unroll
        for (int m = 0; m < 8; ++m) A[m] = Y1[r][refl<W>(c0 - 3 + m)];
#pragma unroll
        for (int m = 0; m < 6; ++m) B[m] = Y2[r][refl<W>(c0 - 2 + m)];
        float acc0 = 0.f, acc1 = 0.f;
#pragma unroll
        for (int t = 0; t < 7; ++t) { acc0 += f0[t] * A[t]; acc1 += f0[t] * A[1 + t]; }
#pragma unroll
        for (int t = 0; t < 5; ++t) { acc0 += f1[t] * B[t]; acc1 += f1[t] * B[1 + t]; }
        *(float2*)(out + ((size_t)nc * H + r0 + r) * W + c0) = make_float2(acc0, acc1);
    }
}

extern "C" void kernel_launch(void* const* d_in, const int* in_sizes, int n_in,
                              void* d_out, int out_size, void* d_ws, size_t ws_size,
                              hipStream_t stream) {
    const float* yl  = (const float*)d_in[0];
    const float* yh0 = (const float*)d_in[1];
    const float* yh1 = (const float*)d_in[2];
    const float* yh2 = (const float*)d_in[3];
    const float* g0o = (const float*)d_in[4];
    const float* g1o = (const float*)d_in[5];
    const float* g0a = (const float*)d_in[6];
    const float* g0b = (const float*)d_in[7];
    const float* g1a = (const float*)d_in[8];
    const float* g1b = (const float*)d_in[9];
    float* out = (float*)d_out;

    char* ws = (char*)d_ws;
    float* bufA = (float*)(ws);                       // ll 256x256: 16 MB
    float* bufB = (float*)(ws + ((size_t)64 << 20));  // ll 512x512: 64 MB

    // Level 2: yl(128x128) + yh2 -> ll(256x256)
    k_i<128, 128, 8><<<dim3(256 / 8, NC), 256, 0, stream>>>(yl, yh2, bufA, g0a, g0b, g1a, g1b);
    // Level 1: ll(256x256) + yh1 -> ll(512x512)
    k_i<256, 256, 8><<<dim3(512 / 8, NC), 256, 0, stream>>>(bufA, yh1, bufB, g0a, g0b, g1a, g1b);
    // Level 0: ll(512x512) + yh0 -> out(512x512)
    k_f0<512, 512, 8><<<dim3(512 / 8, NC), 256, 0, stream>>>(bufB, yh0, out, g0o, g1o);
}

// Round 5
// 137.937 us; speedup vs baseline: 4.4438x; 1.3628x over previous
//
#include <hip/hip_runtime.h>

#define SQH 0.70710678118654752440f
#define NC 64

// Half-sample symmetric reflection, L a compile-time power of two.
// Valid for args in (-2L, 2L): mask then fold.
template<int L>
static __device__ __forceinline__ int refl(int i) {
    int j = i & (2 * L - 1);
    return (j >= L) ? (2 * L - 1 - j) : j;
}

// Direct c2q quad from one band pair (w1,w2) at (ii,jj):
// p0 = (a,b) = values at row 2ii+0, cols (2jj, 2jj+1)
// p1 = (c,d) = values at row 2ii+1, cols (2jj, 2jj+1)
static __device__ __forceinline__ void c2q_quad(float2 w1, float2 w2,
                                                float2& p0, float2& p1) {
    p0 = make_float2(SQH * (w1.x + w2.x), SQH * (w1.y + w2.y));
    p1 = make_float2(SQH * (w1.y - w2.y), SQH * (w2.x - w1.x));
}

static __device__ __forceinline__ void fma2(float2& acc, float s, float2 v) {
    acc.x += s * v.x;
    acc.y += s * v.y;
}

// ---- Fused inverse level: colifilt (c2q fused, both branches) -> LDS -> rowifilt.
// ll: (NC,R_,W_), yh: (NC,6,R_/2,W_/2,2) -> out: (NC,2R_,2W_).
// Block = full-width slab of TY output rows; stage-A task = 2 cols x 4 rows.
template<int R_, int W_, int TY>
__global__ __launch_bounds__(256) void k_i(const float* __restrict__ ll,
                                           const float* __restrict__ yh,
                                           float* __restrict__ out,
                                           const float* __restrict__ g0a, const float* __restrict__ g0b,
                                           const float* __restrict__ g1a, const float* __restrict__ g1b) {
    constexpr int RH = R_ / 2, WH = W_ / 2;
    constexpr int SLABS = 2 * R_ / TY;
    constexpr int PAD = 2;
    __shared__ float Y1[TY][W_ + PAD], Y2[TY][W_ + PAD];

    // XCD-aware decode: each XCD gets a contiguous chunk of (nc, slab) space,
    // so adjacent slabs of the same nc share halo rows in one XCD's L2.
    constexpr int NBLK = SLABS * NC;
    int bid = blockIdx.x;
    int idx = (bid & 7) * (NBLK >> 3) + (bid >> 3);
    int nc = idx / SLABS, slab = idx % SLABS;
    int nc6 = nc * 6;
    int R0 = slab * TY, i0 = R0 >> 2;

    const float2* llp2 = (const float2*)ll + (size_t)nc * R_ * WH;
    const float2* yhp  = (const float2*)yh;
    const float2* pHLa = yhp + (size_t)(nc6 + 2) * RH * WH;
    const float2* pHLb = yhp + (size_t)(nc6 + 3) * RH * WH;
    const float2* pLHa = yhp + (size_t)(nc6 + 0) * RH * WH;
    const float2* pLHb = yhp + (size_t)(nc6 + 5) * RH * WH;
    const float2* pHHa = yhp + (size_t)(nc6 + 1) * RH * WH;
    const float2* pHHb = yhp + (size_t)(nc6 + 4) * RH * WH;

    // ---- Stage A: column inverse filter. Task = col pair jj x 4 output rows.
    constexpr int ATASK = WH * (TY / 4);
    for (int task = threadIdx.x; task < ATASK; task += 256) {
        int jj = task & (WH - 1);
        int gl = task / WH;
        int i  = i0 + gl;

        float2 lE[5], lO[5], hlE[5], hlO[5], lhE[5], lhO[5], hhE[5], hhO[5];
#pragma unroll
        for (int t = 0; t < 5; ++t) {
            int rE = refl<R_>(2 * i - 4 + 2 * t);
            int rO = refl<R_>(2 * i - 3 + 2 * t);
            lE[t] = llp2[(size_t)rE * WH + jj];
            lO[t] = llp2[(size_t)rO * WH + jj];
            int ii = rE >> 1, diE = rE & 1;
            size_t off = (size_t)ii * WH + jj;
            float2 p0, p1;
            c2q_quad(pHLa[off], pHLb[off], p0, p1);
            hlE[t] = diE ? p1 : p0;  hlO[t] = diE ? p0 : p1;
            c2q_quad(pLHa[off], pLHb[off], p0, p1);
            lhE[t] = diE ? p1 : p0;  lhO[t] = diE ? p0 : p1;
            c2q_quad(pHHa[off], pHHb[off], p0, p1);
            hhE[t] = diE ? p1 : p0;  hhO[t] = diE ? p0 : p1;
        }
        float2 a10 = {0, 0}, a20 = {0, 0}, a11 = {0, 0}, a21 = {0, 0};
        float2 a12 = {0, 0}, a22 = {0, 0}, a13 = {0, 0}, a23 = {0, 0};
#pragma unroll
        for (int t = 0; t < 5; ++t) {
            float b0o = g0b[2 * t + 1], a0o = g0a[2 * t + 1];
            float b0e = g0b[2 * t],     a0e = g0a[2 * t];
            float b1o = g1b[2 * t + 1], a1o = g1a[2 * t + 1];
            float b1e = g1b[2 * t],     a1e = g1a[2 * t];
            fma2(a10, b0o, lE[t]);  fma2(a10, b1o, lhO[t]);
            fma2(a20, b0o, hlE[t]); fma2(a20, b1o, hhO[t]);
            fma2(a11, a0o, lO[t]);  fma2(a11, a1o, lhE[t]);
            fma2(a21, a0o, hlO[t]); fma2(a21, a1o, hhE[t]);
            fma2(a12, b0e, lE[t]);  fma2(a12, b1e, lhO[t]);
            fma2(a22, b0e, hlE[t]); fma2(a22, b1e, hhO[t]);
            fma2(a13, a0e, lO[t]);  fma2(a13, a1e, lhE[t]);
            fma2(a23, a0e, hlO[t]); fma2(a23, a1e, hhE[t]);
        }
        int rl = 4 * gl, xc = 2 * jj;
        *(float2*)&Y1[rl + 0][xc] = a10;  *(float2*)&Y2[rl + 0][xc] = a20;
        *(float2*)&Y1[rl + 1][xc] = a11;  *(float2*)&Y2[rl + 1][xc] = a21;
        *(float2*)&Y1[rl + 2][xc] = a12;  *(float2*)&Y2[rl + 2][xc] = a22;
        *(float2*)&Y1[rl + 3][xc] = a13;  *(float2*)&Y2[rl + 3][xc] = a23;
    }
    __syncthreads();

    // ---- Stage B: row inverse filter from LDS. Task = 4 output cols (float4 store).
    constexpr int QW = W_ / 2;   // quads per output row (2W_/4)
    for (int task = threadIdx.x; task < TY * QW; task += 256) {
        int j = task & (QW - 1);
        int r = task / QW;
        float e1[5], o1[5], e2[5], o2[5];
#pragma unroll
        for (int t = 0; t < 5; ++t) {
            int xE = refl<W_>(2 * j - 4 + 2 * t);
            int xO = refl<W_>(2 * j - 3 + 2 * t);
            e1[t] = Y1[r][xE];  o1[t] = Y1[r][xO];
            e2[t] = Y2[r][xE];  o2[t] = Y2[r][xO];
        }
        float4 o = make_float4(0.f, 0.f, 0.f, 0.f);
#pragma unroll
        for (int t = 0; t < 5; ++t) {
            float b0o = g0b[2 * t + 1], a0o = g0a[2 * t + 1];
            float b0e = g0b[2 * t],     a0e = g0a[2 * t];
            float b1o = g1b[2 * t + 1], a1o = g1a[2 * t + 1];
            float b1e = g1b[2 * t],     a1e = g1a[2 * t];
            o.x += b0o * e1[t] + b1o * o2[t];
            o.y += a0o * o1[t] + a1o * e2[t];
            o.z += b0e * e1[t] + b1e * o2[t];
            o.w += a0e * o1[t] + a1e * e2[t];
        }
        *(float4*)(out + ((size_t)nc * (2 * R_) + R0 + r) * (2 * W_) + 4 * j) = o;
    }
}

// ---- Fused final level: colfilter(7/5-tap, c2q fused) -> LDS -> rowfilter.
// ll: (NC,H,W), yh: (NC,6,H/2,W/2,2) -> out: (NC,H,W).
// Block = full-width slab of TY rows; stage-A task = 2 cols x 4 rows.
template<int H, int W, int TY>
__global__ __launch_bounds__(256) void k_f0(const float* __restrict__ ll,
                                            const float* __restrict__ yh,
                                            float* __restrict__ out,
                                            const float* __restrict__ g0o,
                                            const float* __restrict__ g1o) {
    constexpr int RH = H / 2, WH = W / 2;
    constexpr int SLABS = H / TY;
    constexpr int PAD = 2;
    __shared__ float Y1[TY][W + PAD], Y2[TY][W + PAD];

    constexpr int NBLK = SLABS * NC;
    int bid = blockIdx.x;
    int idx = (bid & 7) * (NBLK >> 3) + (bid >> 3);
    int nc = idx / SLABS, slab = idx % SLABS;
    int nc6 = nc * 6;
    int r0 = slab * TY;

    const float2* llp2 = (const float2*)ll + (size_t)nc * H * WH;
    const float2* yhp  = (const float2*)yh;
    const float2* pHLa = yhp + (size_t)(nc6 + 2) * RH * WH;
    const float2* pHLb = yhp + (size_t)(nc6 + 3) * RH * WH;
    const float2* pLHa = yhp + (size_t)(nc6 + 0) * RH * WH;
    const float2* pLHb = yhp + (size_t)(nc6 + 5) * RH * WH;
    const float2* pHHa = yhp + (size_t)(nc6 + 1) * RH * WH;
    const float2* pHHb = yhp + (size_t)(nc6 + 4) * RH * WH;

    float f0[7], f1[5];
#pragma unroll
    for (int k = 0; k < 7; ++k) f0[k] = g0o[k];
#pragma unroll
    for (int k = 0; k < 5; ++k) f1[k] = g1o[k];

    // ---- Stage A: column filter. Task = col pair jj x 4 output rows.
    constexpr int ATASK = WH * (TY / 4);
    for (int task = threadIdx.x; task < ATASK; task += 256) {
        int jj = task & (WH - 1);
        int gl = task / WH;
        int gg = (r0 >> 2) + gl;

        float2 L[10], HL[10], LH[8], HH[8];
#pragma unroll
        for (int t = 0; t < 10; ++t)
            L[t] = llp2[(size_t)refl<H>(4 * gg - 3 + t) * WH + jj];
        // HL window args 4gg-3 .. 4gg+6 -> 6 sibling pairs (ends partial).
#pragma unroll
        for (int pp = 0; pp < 6; ++pp) {
            int rE = refl<H>(4 * gg - 4 + 2 * pp);
            int ii = rE >> 1, diE = rE & 1;
            size_t off = (size_t)ii * WH + jj;
            float2 p0, p1;
            c2q_quad(pHLa[off], pHLb[off], p0, p1);
            float2 vE = diE ? p1 : p0, vO = diE ? p0 : p1;
            if (pp > 0) HL[2 * pp - 1] = vE;
            if (pp < 5) HL[2 * pp]     = vO;
        }
        // LH/HH window args 4gg-2 .. 4gg+5 -> exactly 4 full pairs.
#pragma unroll
        for (int pp = 0; pp < 4; ++pp) {
            int rE = refl<H>(4 * gg - 2 + 2 * pp);
            int ii = rE >> 1, diE = rE & 1;
            size_t off = (size_t)ii * WH + jj;
            float2 p0, p1;
            c2q_quad(pLHa[off], pLHb[off], p0, p1);
            LH[2 * pp]     = diE ? p1 : p0;
            LH[2 * pp + 1] = diE ? p0 : p1;
            c2q_quad(pHHa[off], pHHb[off], p0, p1);
            HH[2 * pp]     = diE ? p1 : p0;
            HH[2 * pp + 1] = diE ? p0 : p1;
        }
        float2 a1[4], a2[4];
#pragma unroll
        for (int q = 0; q < 4; ++q) { a1[q] = make_float2(0.f, 0.f); a2[q] = make_float2(0.f, 0.f); }
#pragma unroll
        for (int q = 0; q < 4; ++q) {
#pragma unroll
            for (int t = 0; t < 7; ++t) { fma2(a1[q], f0[t], L[q + t]);  fma2(a2[q], f0[t], HL[q + t]); }
#pragma unroll
            for (int t = 0; t < 5; ++t) { fma2(a1[q], f1[t], LH[q + t]); fma2(a2[q], f1[t], HH[q + t]); }
        }
        int rl = 4 * gl, xc = 2 * jj;
#pragma unroll
        for (int q = 0; q < 4; ++q) {
            *(float2*)&Y1[rl + q][xc] = a1[q];
            *(float2*)&Y2[rl + q][xc] = a2[q];
        }
    }
    __syncthreads();

    // ---- Stage B: row filter from LDS. Task = 4 output cols (float4 store).
    constexpr int QW = W / 4;
    for (int task = threadIdx.x; task < TY * QW; task += 256) {
        int jq = task & (QW - 1);
        int r  = task / QW;
        int c0 = 4 * jq;
        float A[10], B[8];
#pragma unroll
        for (int m = 0; m < 10; ++m) A[m] = Y1[r][refl<W>(c0 - 3 + m)];
#pragma unroll
        for (int m = 0; m < 8; ++m)  B[m] = Y2[r][refl<W>(c0 - 2 + m)];
        float acc[4] = {0.f, 0.f, 0.f, 0.f};
#pragma unroll
        for (int q = 0; q < 4; ++q) {
#pragma unroll
            for (int t = 0; t < 7; ++t) acc[q] += f0[t] * A[q + t];
#pragma unroll
            for (int t = 0; t < 5; ++t) acc[q] += f1[t] * B[q + t];
        }
        *(float4*)(out + ((size_t)nc * H + r0 + r) * W + c0) =
            make_float4(acc[0], acc[1], acc[2], acc[3]);
    }
}

extern "C" void kernel_launch(void* const* d_in, const int* in_sizes, int n_in,
                              void* d_out, int out_size, void* d_ws, size_t ws_size,
                              hipStream_t stream) {
    const float* yl  = (const float*)d_in[0];
    const float* yh0 = (const float*)d_in[1];
    const float* yh1 = (const float*)d_in[2];
    const float* yh2 = (const float*)d_in[3];
    const float* g0o = (const float*)d_in[4];
    const float* g1o = (const float*)d_in[5];
    const float* g0a = (const float*)d_in[6];
    const float* g0b = (const float*)d_in[7];
    const float* g1a = (const float*)d_in[8];
    const float* g1b = (const float*)d_in[9];
    float* out = (float*)d_out;

    char* ws = (char*)d_ws;
    float* bufA = (float*)(ws);                       // ll 256x256: 16 MB
    float* bufB = (float*)(ws + ((size_t)64 << 20));  // ll 512x512: 64 MB

    // Level 2: yl(128x128) + yh2 -> ll(256x256). 32 slabs x 64 nc = 2048 blocks.
    k_i<128, 128, 8><<<32 * NC, 256, 0, stream>>>(yl, yh2, bufA, g0a, g0b, g1a, g1b);
    // Level 1: ll(256x256) + yh1 -> ll(512x512). 64 slabs x 64 nc = 4096 blocks.
    k_i<256, 256, 8><<<64 * NC, 256, 0, stream>>>(bufA, yh1, bufB, g0a, g0b, g1a, g1b);
    // Level 0: ll(512x512) + yh0 -> out(512x512). 64 slabs x 64 nc = 4096 blocks.
    k_f0<512, 512, 8><<<64 * NC, 256, 0, stream>>>(bufB, yh0, out, g0o, g1o);
}

// Round 6
// 133.367 us; speedup vs baseline: 4.5960x; 1.0343x over previous
//
#include <hip/hip_runtime.h>

#define SQH 0.70710678118654752440f
#define NC 64

// Half-sample symmetric reflection, L a compile-time power of two.
// Valid for args in (-2L, 2L): mask then fold.
template<int L>
static __device__ __forceinline__ int refl(int i) {
    int j = i & (2 * L - 1);
    return (j >= L) ? (2 * L - 1 - j) : j;
}

// Direct c2q quad from one band pair (w1,w2) at (ii,jj):
// p0 = values at row 2ii+0, cols (2jj, 2jj+1); p1 = at row 2ii+1.
static __device__ __forceinline__ void c2q_quad(float2 w1, float2 w2,
                                                float2& p0, float2& p1) {
    p0 = make_float2(SQH * (w1.x + w2.x), SQH * (w1.y + w2.y));
    p1 = make_float2(SQH * (w1.y - w2.y), SQH * (w2.x - w1.x));
}

static __device__ __forceinline__ void fma2(float2& acc, float s, float2 v) {
    acc.x += s * v.x;
    acc.y += s * v.y;
}

// ---- Fused inverse level: colifilt (c2q fused, both branches) -> LDS(+halo) -> rowifilt.
// ll: (NC,R_,W_), yh: (NC,6,R_/2,W_/2,2) -> out: (NC,2R_,2W_).
// Block = full-width slab of TY output rows; stage-A task = 2 cols x 4 rows.
// LDS rows hold [4 left-halo | W_ cols | 5 right-halo] pre-reflected, so stage B
// needs no refl and reads aligned float2 (e,o) pairs.
template<int R_, int W_, int TY>
__global__ __launch_bounds__(256) void k_i(const float* __restrict__ ll,
                                           const float* __restrict__ yh,
                                           float* __restrict__ out,
                                           const float* __restrict__ g0a, const float* __restrict__ g0b,
                                           const float* __restrict__ g1a, const float* __restrict__ g1b) {
    constexpr int RH = R_ / 2, WH = W_ / 2;
    constexpr int SLABS = 2 * R_ / TY;
    constexpr int SW = W_ + 10;          // even stride
    __shared__ float Y1[TY][SW], Y2[TY][SW];

    // XCD-aware decode: contiguous (nc,slab) chunk per XCD for L2 halo sharing.
    constexpr int NBLK = SLABS * NC;
    int bid = blockIdx.x;
    int idx = (bid & 7) * (NBLK >> 3) + (bid >> 3);
    int nc = idx / SLABS, slab = idx % SLABS;
    int nc6 = nc * 6;
    int R0 = slab * TY, i0 = R0 >> 2;
    bool edge = (slab == 0) || (slab == SLABS - 1);

    const float2* llp2 = (const float2*)ll + (size_t)nc * R_ * WH;
    const float2* yhp  = (const float2*)yh;
    const float2* pHLa = yhp + (size_t)(nc6 + 2) * RH * WH;
    const float2* pHLb = yhp + (size_t)(nc6 + 3) * RH * WH;
    const float2* pLHa = yhp + (size_t)(nc6 + 0) * RH * WH;
    const float2* pLHb = yhp + (size_t)(nc6 + 5) * RH * WH;
    const float2* pHHa = yhp + (size_t)(nc6 + 1) * RH * WH;
    const float2* pHHb = yhp + (size_t)(nc6 + 4) * RH * WH;

    // ---- Stage A: column inverse filter. Task = col pair jj x 4 output rows.
    constexpr int ATASK = WH * (TY / 4);
    for (int task = threadIdx.x; task < ATASK; task += 256) {
        int jj = task & (WH - 1);
        int gl = task / WH;
        int i  = i0 + gl;

        float2 lE[5], lO[5], hlE[5], hlO[5], lhE[5], lhO[5], hhE[5], hhO[5];
        if (edge) {
#pragma unroll
            for (int t = 0; t < 5; ++t) {
                int rE = refl<R_>(2 * i - 4 + 2 * t);
                int rO = refl<R_>(2 * i - 3 + 2 * t);
                lE[t] = llp2[(size_t)rE * WH + jj];
                lO[t] = llp2[(size_t)rO * WH + jj];
                int ii = rE >> 1, diE = rE & 1;
                size_t off = (size_t)ii * WH + jj;
                float2 p0, p1;
                c2q_quad(pHLa[off], pHLb[off], p0, p1);
                hlE[t] = diE ? p1 : p0;  hlO[t] = diE ? p0 : p1;
                c2q_quad(pLHa[off], pLHb[off], p0, p1);
                lhE[t] = diE ? p1 : p0;  lhO[t] = diE ? p0 : p1;
                c2q_quad(pHHa[off], pHHb[off], p0, p1);
                hhE[t] = diE ? p1 : p0;  hhO[t] = diE ? p0 : p1;
            }
        } else {
            // Interior: rE = 2i-4+2t (even, diE=0), ii = i-2+t. No refl, no selects.
            const float2* lrow = llp2 + (size_t)(2 * i - 4) * WH + jj;
            size_t off = (size_t)(i - 2) * WH + jj;
#pragma unroll
            for (int t = 0; t < 5; ++t) {
                lE[t] = lrow[(2 * t) * WH];
                lO[t] = lrow[(2 * t + 1) * WH];
                size_t o = off + (size_t)t * WH;
                c2q_quad(pHLa[o], pHLb[o], hlE[t], hlO[t]);
                c2q_quad(pLHa[o], pLHb[o], lhE[t], lhO[t]);
                c2q_quad(pHHa[o], pHHb[o], hhE[t], hhO[t]);
            }
        }
        float2 a10 = {0, 0}, a20 = {0, 0}, a11 = {0, 0}, a21 = {0, 0};
        float2 a12 = {0, 0}, a22 = {0, 0}, a13 = {0, 0}, a23 = {0, 0};
#pragma unroll
        for (int t = 0; t < 5; ++t) {
            float b0o = g0b[2 * t + 1], a0o = g0a[2 * t + 1];
            float b0e = g0b[2 * t],     a0e = g0a[2 * t];
            float b1o = g1b[2 * t + 1], a1o = g1a[2 * t + 1];
            float b1e = g1b[2 * t],     a1e = g1a[2 * t];
            fma2(a10, b0o, lE[t]);  fma2(a10, b1o, lhO[t]);
            fma2(a20, b0o, hlE[t]); fma2(a20, b1o, hhO[t]);
            fma2(a11, a0o, lO[t]);  fma2(a11, a1o, lhE[t]);
            fma2(a21, a0o, hlO[t]); fma2(a21, a1o, hhE[t]);
            fma2(a12, b0e, lE[t]);  fma2(a12, b1e, lhO[t]);
            fma2(a22, b0e, hlE[t]); fma2(a22, b1e, hhO[t]);
            fma2(a13, a0e, lO[t]);  fma2(a13, a1e, lhE[t]);
            fma2(a23, a0e, hlO[t]); fma2(a23, a1e, hhE[t]);
        }
        int rl = 4 * gl, xc = 2 * jj + 4;
        *(float2*)&Y1[rl + 0][xc] = a10;  *(float2*)&Y2[rl + 0][xc] = a20;
        *(float2*)&Y1[rl + 1][xc] = a11;  *(float2*)&Y2[rl + 1][xc] = a21;
        *(float2*)&Y1[rl + 2][xc] = a12;  *(float2*)&Y2[rl + 2][xc] = a22;
        *(float2*)&Y1[rl + 3][xc] = a13;  *(float2*)&Y2[rl + 3][xc] = a23;
    }
    __syncthreads();

    // ---- Halo fill: pre-reflected columns. raw -k -> k-1 ; raw W_+k -> W_-1-k.
    for (int t = threadIdx.x; t < TY * 9; t += 256) {
        int r = t / 9, h = t % 9;
        int dst, src;
        if (h < 4) { dst = h;              src = 4 + 3 - h; }
        else       { int k = h - 4; dst = 4 + W_ + k; src = 4 + W_ - 1 - k; }
        Y1[r][dst] = Y1[r][src];
        Y2[r][dst] = Y2[r][src];
    }
    __syncthreads();

    // ---- Stage B: row inverse filter from LDS. Task = 4 output cols (float4 store).
    constexpr int QW = W_ / 2;
    for (int task = threadIdx.x; task < TY * QW; task += 256) {
        int j = task & (QW - 1);
        int r = task / QW;
        float2 v1[5], v2[5];     // v.x = even series, v.y = odd series
#pragma unroll
        for (int t = 0; t < 5; ++t) {
            v1[t] = *(const float2*)&Y1[r][2 * j + 2 * t];
            v2[t] = *(const float2*)&Y2[r][2 * j + 2 * t];
        }
        float4 o = make_float4(0.f, 0.f, 0.f, 0.f);
#pragma unroll
        for (int t = 0; t < 5; ++t) {
            float b0o = g0b[2 * t + 1], a0o = g0a[2 * t + 1];
            float b0e = g0b[2 * t],     a0e = g0a[2 * t];
            float b1o = g1b[2 * t + 1], a1o = g1a[2 * t + 1];
            float b1e = g1b[2 * t],     a1e = g1a[2 * t];
            o.x += b0o * v1[t].x + b1o * v2[t].y;
            o.y += a0o * v1[t].y + a1o * v2[t].x;
            o.z += b0e * v1[t].x + b1e * v2[t].y;
            o.w += a0e * v1[t].y + a1e * v2[t].x;
        }
        *(float4*)(out + ((size_t)nc * (2 * R_) + R0 + r) * (2 * W_) + 4 * j) = o;
    }
}

// ---- Fused final level: colfilter(7/5-tap, c2q fused) -> LDS(+halo) -> rowfilter.
// ll: (NC,H,W), yh: (NC,6,H/2,W/2,2) -> out: (NC,H,W).
template<int H, int W, int TY>
__global__ __launch_bounds__(256) void k_f0(const float* __restrict__ ll,
                                            const float* __restrict__ yh,
                                            float* __restrict__ out,
                                            const float* __restrict__ g0o,
                                            const float* __restrict__ g1o) {
    constexpr int RH = H / 2, WH = W / 2;
    constexpr int SLABS = H / TY;
    constexpr int SW = W + 10;
    __shared__ float Y1[TY][SW], Y2[TY][SW];

    constexpr int NBLK = SLABS * NC;
    int bid = blockIdx.x;
    int idx = (bid & 7) * (NBLK >> 3) + (bid >> 3);
    int nc = idx / SLABS, slab = idx % SLABS;
    int nc6 = nc * 6;
    int r0 = slab * TY;
    bool edge = (slab == 0) || (slab == SLABS - 1);

    const float2* llp2 = (const float2*)ll + (size_t)nc * H * WH;
    const float2* yhp  = (const float2*)yh;
    const float2* pHLa = yhp + (size_t)(nc6 + 2) * RH * WH;
    const float2* pHLb = yhp + (size_t)(nc6 + 3) * RH * WH;
    const float2* pLHa = yhp + (size_t)(nc6 + 0) * RH * WH;
    const float2* pLHb = yhp + (size_t)(nc6 + 5) * RH * WH;
    const float2* pHHa = yhp + (size_t)(nc6 + 1) * RH * WH;
    const float2* pHHb = yhp + (size_t)(nc6 + 4) * RH * WH;

    float f0[7], f1[5];
#pragma unroll
    for (int k = 0; k < 7; ++k) f0[k] = g0o[k];
#pragma unroll
    for (int k = 0; k < 5; ++k) f1[k] = g1o[k];

    // ---- Stage A: column filter. Task = col pair jj x 4 output rows.
    constexpr int ATASK = WH * (TY / 4);
    for (int task = threadIdx.x; task < ATASK; task += 256) {
        int jj = task & (WH - 1);
        int gl = task / WH;
        int gg = (r0 >> 2) + gl;

        float2 L[10], HL[10], LH[8], HH[8];
        if (edge) {
#pragma unroll
            for (int t = 0; t < 10; ++t)
                L[t] = llp2[(size_t)refl<H>(4 * gg - 3 + t) * WH + jj];
#pragma unroll
            for (int pp = 0; pp < 6; ++pp) {
                int rE = refl<H>(4 * gg - 4 + 2 * pp);
                int ii = rE >> 1, diE = rE & 1;
                size_t off = (size_t)ii * WH + jj;
                float2 p0, p1;
                c2q_quad(pHLa[off], pHLb[off], p0, p1);
                float2 vE = diE ? p1 : p0, vO = diE ? p0 : p1;
                if (pp > 0) HL[2 * pp - 1] = vE;
                if (pp < 5) HL[2 * pp]     = vO;
            }
#pragma unroll
            for (int pp = 0; pp < 4; ++pp) {
                int rE = refl<H>(4 * gg - 2 + 2 * pp);
                int ii = rE >> 1, diE = rE & 1;
                size_t off = (size_t)ii * WH + jj;
                float2 p0, p1;
                c2q_quad(pLHa[off], pLHb[off], p0, p1);
                LH[2 * pp]     = diE ? p1 : p0;
                LH[2 * pp + 1] = diE ? p0 : p1;
                c2q_quad(pHHa[off], pHHb[off], p0, p1);
                HH[2 * pp]     = diE ? p1 : p0;
                HH[2 * pp + 1] = diE ? p0 : p1;
            }
        } else {
            // Interior: no refl, diE = 0 everywhere.
            const float2* lrow = llp2 + (size_t)(4 * gg - 3) * WH + jj;
#pragma unroll
            for (int t = 0; t < 10; ++t) L[t] = lrow[t * WH];
            size_t offHL = (size_t)(2 * gg - 2) * WH + jj;
#pragma unroll
            for (int pp = 0; pp < 6; ++pp) {
                float2 p0, p1;
                c2q_quad(pHLa[offHL + pp * WH], pHLb[offHL + pp * WH], p0, p1);
                if (pp > 0) HL[2 * pp - 1] = p0;
                if (pp < 5) HL[2 * pp]     = p1;
            }
            size_t offL = (size_t)(2 * gg - 1) * WH + jj;
#pragma unroll
            for (int pp = 0; pp < 4; ++pp) {
                float2 p0, p1;
                c2q_quad(pLHa[offL + pp * WH], pLHb[offL + pp * WH], p0, p1);
                LH[2 * pp]     = p0;
                LH[2 * pp + 1] = p1;
                c2q_quad(pHHa[offL + pp * WH], pHHb[offL + pp * WH], p0, p1);
                HH[2 * pp]     = p0;
                HH[2 * pp + 1] = p1;
            }
        }
        float2 a1[4], a2[4];
#pragma unroll
        for (int q = 0; q < 4; ++q) { a1[q] = make_float2(0.f, 0.f); a2[q] = make_float2(0.f, 0.f); }
#pragma unroll
        for (int q = 0; q < 4; ++q) {
#pragma unroll
            for (int t = 0; t < 7; ++t) { fma2(a1[q], f0[t], L[q + t]);  fma2(a2[q], f0[t], HL[q + t]); }
#pragma unroll
            for (int t = 0; t < 5; ++t) { fma2(a1[q], f1[t], LH[q + t]); fma2(a2[q], f1[t], HH[q + t]); }
        }
        int rl = 4 * gl, xc = 2 * jj + 4;
#pragma unroll
        for (int q = 0; q < 4; ++q) {
            *(float2*)&Y1[rl + q][xc] = a1[q];
            *(float2*)&Y2[rl + q][xc] = a2[q];
        }
    }
    __syncthreads();

    // ---- Halo fill.
    for (int t = threadIdx.x; t < TY * 9; t += 256) {
        int r = t / 9, h = t % 9;
        int dst, src;
        if (h < 4) { dst = h;              src = 4 + 3 - h; }
        else       { int k = h - 4; dst = 4 + W + k; src = 4 + W - 1 - k; }
        Y1[r][dst] = Y1[r][src];
        Y2[r][dst] = Y2[r][src];
    }
    __syncthreads();

    // ---- Stage B: row filter from LDS, no refl, aligned float2 reads. 4 cols/task.
    constexpr int QW = W / 4;
    for (int task = threadIdx.x; task < TY * QW; task += 256) {
        int jq = task & (QW - 1);
        int r  = task / QW;
        int c0 = 4 * jq;           // LDS idx c0+k holds raw col c0-4+k
        float a[12], b[8];
#pragma unroll
        for (int m = 0; m < 6; ++m) {
            float2 u = *(const float2*)&Y1[r][c0 + 2 * m];
            a[2 * m] = u.x; a[2 * m + 1] = u.y;
        }
#pragma unroll
        for (int m = 0; m < 4; ++m) {
            float2 u = *(const float2*)&Y2[r][c0 + 2 + 2 * m];
            b[2 * m] = u.x; b[2 * m + 1] = u.y;
        }
        float acc[4] = {0.f, 0.f, 0.f, 0.f};
#pragma unroll
        for (int q = 0; q < 4; ++q) {
#pragma unroll
            for (int t = 0; t < 7; ++t) acc[q] += f0[t] * a[q + t + 1];
#pragma unroll
            for (int t = 0; t < 5; ++t) acc[q] += f1[t] * b[q + t];
        }
        *(float4*)(out + ((size_t)nc * H + r0 + r) * W + c0) =
            make_float4(acc[0], acc[1], acc[2], acc[3]);
    }
}

extern "C" void kernel_launch(void* const* d_in, const int* in_sizes, int n_in,
                              void* d_out, int out_size, void* d_ws, size_t ws_size,
                              hipStream_t stream) {
    const float* yl  = (const float*)d_in[0];
    const float* yh0 = (const float*)d_in[1];
    const float* yh1 = (const float*)d_in[2];
    const float* yh2 = (const float*)d_in[3];
    const float* g0o = (const float*)d_in[4];
    const float* g1o = (const float*)d_in[5];
    const float* g0a = (const float*)d_in[6];
    const float* g0b = (const float*)d_in[7];
    const float* g1a = (const float*)d_in[8];
    const float* g1b = (const float*)d_in[9];
    float* out = (float*)d_out;

    char* ws = (char*)d_ws;
    float* bufA = (float*)(ws);                       // ll 256x256: 16 MB
    float* bufB = (float*)(ws + ((size_t)64 << 20));  // ll 512x512: 64 MB

    // Level 2: yl(128x128) + yh2 -> ll(256x256). 32 slabs x 64 nc.
    k_i<128, 128, 8><<<32 * NC, 256, 0, stream>>>(yl, yh2, bufA, g0a, g0b, g1a, g1b);
    // Level 1: ll(256x256) + yh1 -> ll(512x512). 64 slabs x 64 nc.
    k_i<256, 256, 8><<<64 * NC, 256, 0, stream>>>(bufA, yh1, bufB, g0a, g0b, g1a, g1b);
    // Level 0: ll(512x512) + yh0 -> out(512x512). 64 slabs x 64 nc.
    k_f0<512, 512, 8><<<64 * NC, 256, 0, stream>>>(bufB, yh0, out, g0o, g1o);
}

// Round 8
// 103.344 us; speedup vs baseline: 5.9313x; 1.2905x over previous
//
#include <hip/hip_runtime.h>
#include <hip/hip_fp16.h>

#define SQH 0.70710678118654752440f
#define NC 64

typedef float nfloat4 __attribute__((ext_vector_type(4)));

// Half-sample symmetric reflection, L a compile-time power of two.
template<int L>
static __device__ __forceinline__ int refl(int i) {
    int j = i & (2 * L - 1);
    return (j >= L) ? (2 * L - 1 - j) : j;
}

// c2q on a float4 = two adjacent complex pairs (cols 2jj..2jj+3).
// p0 = values at even row (2ii), p1 = values at odd row (2ii+1).
static __device__ __forceinline__ void c2q_quad4(float4 A, float4 B,
                                                 float4& p0, float4& p1) {
    p0 = make_float4(SQH * (A.x + B.x), SQH * (A.y + B.y),
                     SQH * (A.z + B.z), SQH * (A.w + B.w));
    p1 = make_float4(SQH * (A.y - B.y), SQH * (B.x - A.x),
                     SQH * (A.w - B.w), SQH * (B.z - A.z));
}

static __device__ __forceinline__ void fma4(float4& a, float s, float4 v) {
    a.x += s * v.x; a.y += s * v.y; a.z += s * v.z; a.w += s * v.w;
}

// 4-element group load/store, fp32 or fp16 backing.
static __device__ __forceinline__ float4 ld4(const float* p, size_t i4) {
    return ((const float4*)p)[i4];
}
static __device__ __forceinline__ float4 ld4(const __half* p, size_t i4) {
    const __half2* h = (const __half2*)p;
    float2 lo = __half22float2(h[2 * i4]);
    float2 hi = __half22float2(h[2 * i4 + 1]);
    return make_float4(lo.x, lo.y, hi.x, hi.y);
}
static __device__ __forceinline__ void st4(float* p, size_t i4, float4 v) {
    ((float4*)p)[i4] = v;
}
static __device__ __forceinline__ void st4(__half* p, size_t i4, float4 v) {
    __half2* h = (__half2*)p;
    h[2 * i4]     = __float22half2_rn(make_float2(v.x, v.y));
    h[2 * i4 + 1] = __float22half2_rn(make_float2(v.z, v.w));
}

// ---- Fused inverse level: colifilt (c2q fused, both branches) -> LDS(+halo) -> rowifilt.
// ll: (NC,R_,W_), yh: (NC,6,R_/2,W_/2,2) -> out: (NC,2R_,2W_).
// Stage-A task = 4 cols x 4 rows, loads fused with accumulation (low VGPR).
template<int R_, int W_, int TY, typename InT, typename OutT>
__global__ __launch_bounds__(256) void k_i(const InT* __restrict__ ll,
                                           const float* __restrict__ yh,
                                           OutT* __restrict__ out,
                                           const float* __restrict__ g0a, const float* __restrict__ g0b,
                                           const float* __restrict__ g1a, const float* __restrict__ g1b) {
    constexpr int RH = R_ / 2, WH = W_ / 2, WQ = W_ / 4;
    constexpr int SLABS = 2 * R_ / TY;
    constexpr int SW = W_ + 12;
    __shared__ float Y1[TY][SW], Y2[TY][SW];

    constexpr int NBLK = SLABS * NC;
    int bid = blockIdx.x;
    int idx = (bid & 7) * (NBLK >> 3) + (bid >> 3);
    int nc = idx / SLABS, slab = idx % SLABS;
    int nc6 = nc * 6;
    int R0 = slab * TY, i0 = R0 >> 2;
    bool edge = (slab == 0) || (slab == SLABS - 1);

    const InT* llp = ll + (size_t)nc * R_ * W_;
    const float4* yh4 = (const float4*)yh;
    const float4* pHLa = yh4 + (size_t)(nc6 + 2) * RH * WQ;
    const float4* pHLb = yh4 + (size_t)(nc6 + 3) * RH * WQ;
    const float4* pLHa = yh4 + (size_t)(nc6 + 0) * RH * WQ;
    const float4* pLHb = yh4 + (size_t)(nc6 + 5) * RH * WQ;
    const float4* pHHa = yh4 + (size_t)(nc6 + 1) * RH * WQ;
    const float4* pHHb = yh4 + (size_t)(nc6 + 4) * RH * WQ;

    // ---- Stage A: column inverse filter. Task = 4 cols x 4 output rows.
    constexpr int ATASK = WQ * (TY / 4);
    for (int task = threadIdx.x; task < ATASK; task += 256) {
        int jq = task & (WQ - 1);
        int gl = task / WQ;
        int i  = i0 + gl;

        float4 a10 = {0,0,0,0}, a20 = {0,0,0,0}, a11 = {0,0,0,0}, a21 = {0,0,0,0};
        float4 a12 = {0,0,0,0}, a22 = {0,0,0,0}, a13 = {0,0,0,0}, a23 = {0,0,0,0};
#pragma unroll
        for (int t = 0; t < 5; ++t) {
            float4 lE, lO, hlE, hlO, lhE, lhO, hhE, hhO;
            if (edge) {
                int rE = refl<R_>(2 * i - 4 + 2 * t);
                int rO = refl<R_>(2 * i - 3 + 2 * t);
                lE = ld4(llp, (size_t)rE * WQ + jq);
                lO = ld4(llp, (size_t)rO * WQ + jq);
                int ii = rE >> 1, diE = rE & 1;
                size_t off = (size_t)ii * WQ + jq;
                float4 p0, p1;
                c2q_quad4(pHLa[off], pHLb[off], p0, p1);
                hlE = diE ? p1 : p0;  hlO = diE ? p0 : p1;
                c2q_quad4(pLHa[off], pLHb[off], p0, p1);
                lhE = diE ? p1 : p0;  lhO = diE ? p0 : p1;
                c2q_quad4(pHHa[off], pHHb[off], p0, p1);
                hhE = diE ? p1 : p0;  hhO = diE ? p0 : p1;
            } else {
                lE = ld4(llp, (size_t)(2 * i - 4 + 2 * t) * WQ + jq);
                lO = ld4(llp, (size_t)(2 * i - 3 + 2 * t) * WQ + jq);
                size_t off = (size_t)(i - 2 + t) * WQ + jq;
                c2q_quad4(pHLa[off], pHLb[off], hlE, hlO);
                c2q_quad4(pLHa[off], pLHb[off], lhE, lhO);
                c2q_quad4(pHHa[off], pHHb[off], hhE, hhO);
            }
            float b0o = g0b[2 * t + 1], a0o = g0a[2 * t + 1];
            float b0e = g0b[2 * t],     a0e = g0a[2 * t];
            float b1o = g1b[2 * t + 1], a1o = g1a[2 * t + 1];
            float b1e = g1b[2 * t],     a1e = g1a[2 * t];
            fma4(a10, b0o, lE);  fma4(a10, b1o, lhO);
            fma4(a20, b0o, hlE); fma4(a20, b1o, hhO);
            fma4(a11, a0o, lO);  fma4(a11, a1o, lhE);
            fma4(a21, a0o, hlO); fma4(a21, a1o, hhE);
            fma4(a12, b0e, lE);  fma4(a12, b1e, lhO);
            fma4(a22, b0e, hlE); fma4(a22, b1e, hhO);
            fma4(a13, a0e, lO);  fma4(a13, a1e, lhE);
            fma4(a23, a0e, hlO); fma4(a23, a1e, hhE);
        }
        int rl = 4 * gl, xc = 4 * jq + 4;
        *(float4*)&Y1[rl + 0][xc] = a10;  *(float4*)&Y2[rl + 0][xc] = a20;
        *(float4*)&Y1[rl + 1][xc] = a11;  *(float4*)&Y2[rl + 1][xc] = a21;
        *(float4*)&Y1[rl + 2][xc] = a12;  *(float4*)&Y2[rl + 2][xc] = a22;
        *(float4*)&Y1[rl + 3][xc] = a13;  *(float4*)&Y2[rl + 3][xc] = a23;
    }
    __syncthreads();

    // ---- Halo fill (pre-reflected cols): raw -k -> k-1 ; raw W_+k -> W_-1-k.
    for (int t = threadIdx.x; t < TY * 9; t += 256) {
        int r = t / 9, h = t % 9;
        int dst, src;
        if (h < 4) { dst = h;              src = 7 - h; }
        else       { int k = h - 4; dst = 4 + W_ + k; src = 4 + W_ - 1 - k; }
        Y1[r][dst] = Y1[r][src];
        Y2[r][dst] = Y2[r][src];
    }
    __syncthreads();

    // ---- Stage B: row inverse filter from LDS (no refl, aligned float2 reads).
    constexpr int QW = W_ / 2;   // quads per output row
    for (int task = threadIdx.x; task < TY * QW; task += 256) {
        int j = task & (QW - 1);
        int r = task / QW;
        float2 v1[5], v2[5];     // .x = even series, .y = odd series
#pragma unroll
        for (int t = 0; t < 5; ++t) {
            v1[t] = *(const float2*)&Y1[r][2 * j + 2 * t];
            v2[t] = *(const float2*)&Y2[r][2 * j + 2 * t];
        }
        float4 o = make_float4(0.f, 0.f, 0.f, 0.f);
#pragma unroll
        for (int t = 0; t < 5; ++t) {
            float b0o = g0b[2 * t + 1], a0o = g0a[2 * t + 1];
            float b0e = g0b[2 * t],     a0e = g0a[2 * t];
            float b1o = g1b[2 * t + 1], a1o = g1a[2 * t + 1];
            float b1e = g1b[2 * t],     a1e = g1a[2 * t];
            o.x += b0o * v1[t].x + b1o * v2[t].y;
            o.y += a0o * v1[t].y + a1o * v2[t].x;
            o.z += b0e * v1[t].x + b1e * v2[t].y;
            o.w += a0e * v1[t].y + a1e * v2[t].x;
        }
        st4(out, (size_t)(nc * 2 * R_ + R0 + r) * QW + j, o);
    }
}

// ---- Fused final level: colfilter(7/5-tap, c2q fused) -> LDS(+halo) -> rowfilter.
// ll: (NC,H,W) fp16, yh: (NC,6,H/2,W/2,2) -> out: (NC,H,W) fp32 nt-store.
template<int H, int W, int TY, typename InT>
__global__ __launch_bounds__(256) void k_f0(const InT* __restrict__ ll,
                                            const float* __restrict__ yh,
                                            float* __restrict__ out,
                                            const float* __restrict__ g0o,
                                            const float* __restrict__ g1o) {
    constexpr int RH = H / 2, WH = W / 2, WQ = W / 4;
    constexpr int SLABS = H / TY;
    constexpr int SW = W + 12;
    __shared__ float Y1[TY][SW], Y2[TY][SW];

    constexpr int NBLK = SLABS * NC;
    int bid = blockIdx.x;
    int idx = (bid & 7) * (NBLK >> 3) + (bid >> 3);
    int nc = idx / SLABS, slab = idx % SLABS;
    int nc6 = nc * 6;
    int r0 = slab * TY;
    bool edge = (slab == 0) || (slab == SLABS - 1);

    const InT* llp = ll + (size_t)nc * H * W;
    const float4* yh4 = (const float4*)yh;
    const float4* pHLa = yh4 + (size_t)(nc6 + 2) * RH * WQ;
    const float4* pHLb = yh4 + (size_t)(nc6 + 3) * RH * WQ;
    const float4* pLHa = yh4 + (size_t)(nc6 + 0) * RH * WQ;
    const float4* pLHb = yh4 + (size_t)(nc6 + 5) * RH * WQ;
    const float4* pHHa = yh4 + (size_t)(nc6 + 1) * RH * WQ;
    const float4* pHHb = yh4 + (size_t)(nc6 + 4) * RH * WQ;

    float f0[7], f1[5];
#pragma unroll
    for (int k = 0; k < 7; ++k) f0[k] = g0o[k];
#pragma unroll
    for (int k = 0; k < 5; ++k) f1[k] = g1o[k];

    // ---- Stage A: column filter. Task = 4 cols x 4 output rows, fused loads+fma.
    constexpr int ATASK = WQ * (TY / 4);
    for (int task = threadIdx.x; task < ATASK; task += 256) {
        int jq = task & (WQ - 1);
        int gl = task / WQ;
        int gg = (r0 >> 2) + gl;

        float4 a1[4], a2[4];
#pragma unroll
        for (int q = 0; q < 4; ++q) { a1[q] = make_float4(0,0,0,0); a2[q] = make_float4(0,0,0,0); }

        // Lowpass path from ll: window rows 4gg-3+m, m=0..9, 7-tap f0.
#pragma unroll
        for (int m = 0; m < 10; ++m) {
            float4 v;
            if (edge) v = ld4(llp, (size_t)refl<H>(4 * gg - 3 + m) * WQ + jq);
            else      v = ld4(llp, (size_t)(4 * gg - 3 + m) * WQ + jq);
#pragma unroll
            for (int q = 0; q < 4; ++q)
                if (m - q >= 0 && m - q < 7) fma4(a1[q], f0[m - q], v);
        }
        // HL band (7-tap f0 into a2): pairs pp cover window m = 2pp-1 (E), 2pp (O).
#pragma unroll
        for (int pp = 0; pp < 6; ++pp) {
            float4 vE, vO, p0, p1;
            if (edge) {
                int rE = refl<H>(4 * gg - 4 + 2 * pp);
                int ii = rE >> 1, diE = rE & 1;
                size_t off = (size_t)ii * WQ + jq;
                c2q_quad4(pHLa[off], pHLb[off], p0, p1);
                vE = diE ? p1 : p0;  vO = diE ? p0 : p1;
            } else {
                size_t off = (size_t)(2 * gg - 2 + pp) * WQ + jq;
                c2q_quad4(pHLa[off], pHLb[off], vE, vO);
            }
            if (pp > 0) {
                int m = 2 * pp - 1;
#pragma unroll
                for (int q = 0; q < 4; ++q)
                    if (m - q >= 0 && m - q < 7) fma4(a2[q], f0[m - q], vE);
            }
            if (pp < 5) {
                int m = 2 * pp;
#pragma unroll
                for (int q = 0; q < 4; ++q)
                    if (m - q >= 0 && m - q < 7) fma4(a2[q], f0[m - q], vO);
            }
        }
        // LH (f1 into a1) and HH (f1 into a2): pairs pp -> window m = 2pp (E), 2pp+1 (O).
#pragma unroll
        for (int pp = 0; pp < 4; ++pp) {
            float4 vE, vO, p0, p1;
            size_t off;
            int diE = 0;
            if (edge) {
                int rE = refl<H>(4 * gg - 2 + 2 * pp);
                diE = rE & 1;
                off = (size_t)(rE >> 1) * WQ + jq;
            } else {
                off = (size_t)(2 * gg - 1 + pp) * WQ + jq;
            }
            c2q_quad4(pLHa[off], pLHb[off], p0, p1);
            vE = diE ? p1 : p0;  vO = diE ? p0 : p1;
            {
                int m = 2 * pp;
#pragma unroll
                for (int q = 0; q < 4; ++q)
                    if (m - q >= 0 && m - q < 5) fma4(a1[q], f1[m - q], vE);
            }
            {
                int m = 2 * pp + 1;
#pragma unroll
                for (int q = 0; q < 4; ++q)
                    if (m - q >= 0 && m - q < 5) fma4(a1[q], f1[m - q], vO);
            }
            c2q_quad4(pHHa[off], pHHb[off], p0, p1);
            vE = diE ? p1 : p0;  vO = diE ? p0 : p1;
            {
                int m = 2 * pp;
#pragma unroll
                for (int q = 0; q < 4; ++q)
                    if (m - q >= 0 && m - q < 5) fma4(a2[q], f1[m - q], vE);
            }
            {
                int m = 2 * pp + 1;
#pragma unroll
                for (int q = 0; q < 4; ++q)
                    if (m - q >= 0 && m - q < 5) fma4(a2[q], f1[m - q], vO);
            }
        }
        int rl = 4 * gl, xc = 4 * jq + 4;
#pragma unroll
        for (int q = 0; q < 4; ++q) {
            *(float4*)&Y1[rl + q][xc] = a1[q];
            *(float4*)&Y2[rl + q][xc] = a2[q];
        }
    }
    __syncthreads();

    // ---- Halo fill.
    for (int t = threadIdx.x; t < TY * 9; t += 256) {
        int r = t / 9, h = t % 9;
        int dst, src;
        if (h < 4) { dst = h;              src = 7 - h; }
        else       { int k = h - 4; dst = 4 + W + k; src = 4 + W - 1 - k; }
        Y1[r][dst] = Y1[r][src];
        Y2[r][dst] = Y2[r][src];
    }
    __syncthreads();

    // ---- Stage B: row filter from LDS, no refl, aligned float2 reads; nt float4 store.
    constexpr int QW = W / 4;
    for (int task = threadIdx.x; task < TY * QW; task += 256) {
        int jq = task & (QW - 1);
        int r  = task / QW;
        int c0 = 4 * jq;           // LDS idx c0+k holds raw col c0-4+k
        float a[12], b[8];
#pragma unroll
        for (int m = 0; m < 6; ++m) {
            float2 u = *(const float2*)&Y1[r][c0 + 2 * m];
            a[2 * m] = u.x; a[2 * m + 1] = u.y;
        }
#pragma unroll
        for (int m = 0; m < 4; ++m) {
            float2 u = *(const float2*)&Y2[r][c0 + 2 + 2 * m];
            b[2 * m] = u.x; b[2 * m + 1] = u.y;
        }
        float acc[4] = {0.f, 0.f, 0.f, 0.f};
#pragma unroll
        for (int q = 0; q < 4; ++q) {
#pragma unroll
            for (int t = 0; t < 7; ++t) acc[q] += f0[t] * a[q + t + 1];
#pragma unroll
            for (int t = 0; t < 5; ++t) acc[q] += f1[t] * b[q + t];
        }
        nfloat4 nv = {acc[0], acc[1], acc[2], acc[3]};
        __builtin_nontemporal_store(nv,
            (nfloat4*)(out + ((size_t)nc * H + r0 + r) * W + c0));
    }
}

extern "C" void kernel_launch(void* const* d_in, const int* in_sizes, int n_in,
                              void* d_out, int out_size, void* d_ws, size_t ws_size,
                              hipStream_t stream) {
    const float* yl  = (const float*)d_in[0];
    const float* yh0 = (const float*)d_in[1];
    const float* yh1 = (const float*)d_in[2];
    const float* yh2 = (const float*)d_in[3];
    const float* g0o = (const float*)d_in[4];
    const float* g1o = (const float*)d_in[5];
    const float* g0a = (const float*)d_in[6];
    const float* g0b = (const float*)d_in[7];
    const float* g1a = (const float*)d_in[8];
    const float* g1b = (const float*)d_in[9];
    float* out = (float*)d_out;

    char* ws = (char*)d_ws;
    __half* bufA = (__half*)(ws);                       // ll 256x256 fp16: 8.4 MB
    __half* bufB = (__half*)(ws + ((size_t)64 << 20));  // ll 512x512 fp16: 33.6 MB

    // Level 2: yl(128x128) fp32 + yh2 -> ll(256x256) fp16. 8 slabs x 64 nc.
    k_i<128, 128, 32, float, __half><<<8 * NC, 256, 0, stream>>>(
        yl, yh2, bufA, g0a, g0b, g1a, g1b);
    // Level 1: ll(256x256) fp16 + yh1 -> ll(512x512) fp16. 32 slabs x 64 nc.
    k_i<256, 256, 16, __half, __half><<<32 * NC, 256, 0, stream>>>(
        bufA, yh1, bufB, g0a, g0b, g1a, g1b);
    // Level 0: ll(512x512) fp16 + yh0 -> out(512x512) fp32. 64 slabs x 64 nc.
    k_f0<512, 512, 8, __half><<<64 * NC, 256, 0, stream>>>(
        bufB, yh0, out, g0o, g1o);
}